// Round 1
// baseline (1279.135 us; speedup 1.0000x reference)
//
#include <hip/hip_runtime.h>
#include <math.h>

#define VOCAB 32768
#define DD 512
#define NB 3
#define NF 3
#define SEQ 4
#define MAX_ENT_F 10.3972077083991790f

// ---------------- reduction helpers ----------------
__device__ __forceinline__ float blockReduceSum(float v, float* sh) {
  int lane = threadIdx.x & 63;
  int wid  = threadIdx.x >> 6;
#pragma unroll
  for (int off = 32; off; off >>= 1) v += __shfl_down(v, off, 64);
  __syncthreads();                    // protect sh reuse across calls
  if (lane == 0) sh[wid] = v;
  __syncthreads();
  int nw = blockDim.x >> 6;
  float r = 0.0f;
  if ((int)threadIdx.x < nw) r = sh[threadIdx.x];
  if (wid == 0) {
#pragma unroll
    for (int off = 8; off; off >>= 1) r += __shfl_down(r, off, 64);
    if (lane == 0) sh[0] = r;
  }
  __syncthreads();
  return sh[0];
}

// ---------------- kernels ----------------
__global__ void k_zero(float* p, int n) {
  int i = blockIdx.x * blockDim.x + threadIdx.x;
  if (i < n) p[i] = 0.0f;
}

// per-foam: mem_mean, novelty, decay, xin = x + decay*mem_mean
__global__ void k_pre(const int* __restrict__ tokens, const float* __restrict__ E,
                      const float* __restrict__ mem, float* __restrict__ xin,
                      float* __restrict__ decayArr, const float* __restrict__ base_p,
                      const float* __restrict__ sens_p, int t) {
  const int f = blockIdx.x, tid = threadIdx.x;     // 256 threads
  __shared__ float smean[DD];
  __shared__ float red[16];
  __shared__ float s_decay;
  const float* x = E + (size_t)tokens[t] * DD;
  const float* m = mem + f * (NB * DD);
  for (int d = tid; d < DD; d += 256)
    smean[d] = (m[d] + m[DD + d] + m[2 * DD + d]) * (1.0f / 3.0f);
  __syncthreads();
  float pxm = 0.f, pxx = 0.f, pmm = 0.f;
  for (int d = tid; d < DD; d += 256) {
    float xv = x[d], mv = smean[d];
    pxm += xv * mv; pxx += xv * xv; pmm += mv * mv;
  }
  float sxm = blockReduceSum(pxm, red);
  float sxx = blockReduceSum(pxx, red);
  float smm = blockReduceSum(pmm, red);
  if (tid == 0) {
    float mem_norm = sqrtf(smm) + 1e-10f;
    float x_norm   = sqrtf(sxx) + 1e-10f;
    float novelty  = (mem_norm > 1e-8f) ? (1.0f - sxm / (x_norm * mem_norm)) : 1.0f;
    float sens = fabsf(sens_p[0]);
    float z = base_p[0] - sens * novelty;
    float dec = 1.0f / (1.0f + expf(-z));
    decayArr[f] = dec;
    s_decay = dec;
  }
  __syncthreads();
  float dec = s_decay;
  for (int d = tid; d < DD; d += 256)
    xin[f * DD + d] = x[d] + dec * smean[d];
}

// states[f][n][e] = sum_d xin[f][d] * Ws[f][n][d][e]
__global__ void k_states(const float* __restrict__ Ws, const float* __restrict__ xin,
                         float* __restrict__ states) {
  const int fn = blockIdx.x;             // 0..8
  const int f = fn / NB;
  const int e = blockIdx.y * 128 + threadIdx.x;
  __shared__ float sx[DD];
  for (int d = threadIdx.x; d < DD; d += 128) sx[d] = xin[f * DD + d];
  __syncthreads();
  const float* W = Ws + (size_t)fn * DD * DD + e;
  float acc = 0.f;
#pragma unroll 8
  for (int d = 0; d < DD; d++) acc += sx[d] * W[(size_t)d * DD];
  states[fn * DD + e] = acc;
}

// equilibrate, norms, bubble weights, normed, memory update, bmax init
__global__ void k_equil(const float* __restrict__ states, float* __restrict__ mem,
                        float* __restrict__ normed, float* __restrict__ wbub,
                        const float* __restrict__ decayArr, int* __restrict__ bmaxI) {
  const int f = blockIdx.x, tid = threadIdx.x;   // 256 threads
  __shared__ float s[NB * DD];
  __shared__ float red[16];
  __shared__ float snrm[NB];
  for (int i = tid; i < NB * DD; i += 256) s[i] = states[f * NB * DD + i];
  __syncthreads();
  for (int e = tid; e < DD; e += 256) {
    float a = s[e], b = s[DD + e], c = s[2 * DD + e];
#pragma unroll
    for (int it = 0; it < 3; it++) {
      float mn = (a + b + c) * (1.0f / 3.0f);
      a += 0.3f * (mn - a);
      b += 0.3f * (mn - b);
      c += 0.3f * (mn - c);
    }
    s[e] = a; s[DD + e] = b; s[2 * DD + e] = c;
  }
  __syncthreads();
  for (int n = 0; n < NB; n++) {
    float p = 0.f;
    for (int e = tid; e < DD; e += 256) { float v = s[n * DD + e]; p += v * v; }
    float ss = blockReduceSum(p, red);
    if (tid == 0) snrm[n] = sqrtf(ss);
  }
  __syncthreads();
  if (tid == 0) {
    float n0 = snrm[0], n1 = snrm[1], n2 = snrm[2];
    float mx = fmaxf(2.0f * n0, fmaxf(2.0f * n1, 2.0f * n2));
    float e0 = expf(2.0f * n0 - mx), e1 = expf(2.0f * n1 - mx), e2 = expf(2.0f * n2 - mx);
    float sd = e0 + e1 + e2;
    wbub[f * NB + 0] = e0 / sd;
    wbub[f * NB + 1] = e1 / sd;
    wbub[f * NB + 2] = e2 / sd;
    bmaxI[f] = 0;   // born >= 0 so 0 is a safe lower bound
  }
  float dec = decayArr[f];
  for (int i = tid; i < NB * DD; i += 256) {
    int n = i >> 9;
    float sv = s[i];
    normed[f * NB * DD + i] = sv / (snrm[n] + 1e-10f);
    float old = mem[f * NB * DD + i];
    mem[f * NB * DD + i] = dec * old + (1.0f - dec) * sv;
  }
}

// born_f[v] = sum_n wbub[f][n] * (E_v . normed[f][n])^2 ; atomic max per foam
__global__ __launch_bounds__(256) void k_born(const float4* __restrict__ E4,
                                              const float4* __restrict__ N4,
                                              const float* __restrict__ wbub,
                                              float* __restrict__ born,
                                              int* __restrict__ bmaxI) {
  const int tid = threadIdx.x, lane = tid & 63, wave = tid >> 6;
  float4 nr0[9], nr1[9];
#pragma unroll
  for (int j = 0; j < 9; j++) {
    nr0[j] = N4[j * 128 + lane];
    nr1[j] = N4[j * 128 + 64 + lane];
  }
  __shared__ float w9[9];
  __shared__ float sb[3][4];
  if (tid < 9) w9[tid] = wbub[tid];
  __syncthreads();
  float bm0 = 0.f, bm1 = 0.f, bm2 = 0.f;
  const int vbase = blockIdx.x * 16 + wave * 4;
#pragma unroll
  for (int r = 0; r < 4; r++) {
    int v = vbase + r;
    float4 a0 = E4[v * 128 + lane];
    float4 a1 = E4[v * 128 + 64 + lane];
    float acc[9];
#pragma unroll
    for (int j = 0; j < 9; j++) {
      float4 p = nr0[j], q = nr1[j];
      acc[j] = a0.x * p.x + a0.y * p.y + a0.z * p.z + a0.w * p.w +
               a1.x * q.x + a1.y * q.y + a1.z * q.z + a1.w * q.w;
    }
#pragma unroll
    for (int j = 0; j < 9; j++) {
      float a = acc[j];
#pragma unroll
      for (int off = 32; off; off >>= 1) a += __shfl_down(a, off, 64);
      acc[j] = a;
    }
    if (lane == 0) {
      float b0 = w9[0] * acc[0] * acc[0] + w9[1] * acc[1] * acc[1] + w9[2] * acc[2] * acc[2];
      float b1 = w9[3] * acc[3] * acc[3] + w9[4] * acc[4] * acc[4] + w9[5] * acc[5] * acc[5];
      float b2 = w9[6] * acc[6] * acc[6] + w9[7] * acc[7] * acc[7] + w9[8] * acc[8] * acc[8];
      born[v] = b0; born[VOCAB + v] = b1; born[2 * VOCAB + v] = b2;
      bm0 = fmaxf(bm0, b0); bm1 = fmaxf(bm1, b1); bm2 = fmaxf(bm2, b2);
    }
  }
  if (lane == 0) { sb[0][wave] = bm0; sb[1][wave] = bm1; sb[2][wave] = bm2; }
  __syncthreads();
  if (tid < 3) {
    float m = fmaxf(fmaxf(sb[tid][0], sb[tid][1]), fmaxf(sb[tid][2], sb[tid][3]));
    atomicMax(&bmaxI[tid], __float_as_int(m));
  }
}

// per-foam softmax in place (born -> dists), entropy -> concentration, sum p^2, logS
__global__ void k_softmax(float* __restrict__ dist, const int* __restrict__ bmaxI,
                          float* __restrict__ conc, float* __restrict__ sumsq,
                          float* __restrict__ logSArr) {
  const int f = blockIdx.x, tid = threadIdx.x;   // 1024 threads
  __shared__ float red[16];
  const float bmax = __int_as_float(bmaxI[f]);
  float* arr = dist + f * VOCAB;
  float se = 0.f;
  for (int v = tid; v < VOCAB; v += blockDim.x) se += expf(arr[v] - bmax);
  float S = blockReduceSum(se, red);
  float lgS = logf(S);
  float pl = 0.f, sq = 0.f;
  for (int v = tid; v < VOCAB; v += blockDim.x) {
    float t = arr[v] - bmax - lgS;
    float p = expf(t);
    arr[v] = p;
    pl += p * fmaxf(t, -100.0f);
    sq += p * p;
  }
  float spl = blockReduceSum(pl, red);
  float ssq = blockReduceSum(sq, red);
  if (tid == 0) {
    conc[f] = 1.0f + spl / MAX_ENT_F;     // 1 - (-spl)/MAX_ENT
    sumsq[f] = ssq;
    logSArr[f] = lgS;
  }
}

// pairwise sums dist_a . dist_b for pairs (0,1),(0,2),(1,2)
__global__ void k_cross(const float* __restrict__ dist, float* __restrict__ cross) {
  const int p = blockIdx.x, tid = threadIdx.x;  // 1024 threads
  const int a = (p < 2) ? 0 : 1;
  const int b = (p == 0) ? 1 : 2;
  const float* A = dist + a * VOCAB;
  const float* B = dist + b * VOCAB;
  __shared__ float red[16];
  float s = 0.f;
  for (int v = tid; v < VOCAB; v += blockDim.x) s += A[v] * B[v];
  float t = blockReduceSum(s, red);
  if (tid == 0) cross[p] = t;
}

// meta weights, coefficients, 9x9 spectrum -> S_rho
__global__ void k_meta(const float* __restrict__ normed, const float* __restrict__ wbub,
                       const float* __restrict__ conc, const float* __restrict__ sumsq,
                       const float* __restrict__ cross, const float* __restrict__ temp_p,
                       float* __restrict__ o_w, float* __restrict__ o_sr,
                       float* __restrict__ wmeta, float* __restrict__ coeff,
                       float* __restrict__ srho_ws) {
  const int tid = threadIdx.x;   // 256 threads
  __shared__ float red[16];
  __shared__ float G[45];
  for (int p = 0; p < 45; p++) {
    int i = 0, jj = p;
    while (jj >= 9 - i) { jj -= 9 - i; i++; }
    int j = i + jj;
    const float* ni = normed + i * DD;
    const float* nj = normed + j * DD;
    float s = 0.f;
    for (int d = tid; d < DD; d += blockDim.x) s += ni[d] * nj[d];
    float tot = blockReduceSum(s, red);
    if (tid == 0) G[p] = tot;
  }
  __syncthreads();
  if (tid == 0) {
    float np0 = sqrtf(sumsq[0]) + 1e-10f;
    float np1 = sqrtf(sumsq[1]) + 1e-10f;
    float np2 = sqrtf(sumsq[2]) + 1e-10f;
    float A01 = cross[0] / (np0 * np1);
    float A02 = cross[1] / (np0 * np2);
    float A12 = cross[2] / (np1 * np2);
    float ag0 = 0.5f * (A01 + A02);
    float ag1 = 0.5f * (A01 + A12);
    float ag2 = 0.5f * (A02 + A12);
    float temp = fmaxf(fabsf(temp_p[0]), 0.01f);
    float z0 = conc[0] * ag0 / temp, z1 = conc[1] * ag1 / temp, z2 = conc[2] * ag2 / temp;
    float mz = fmaxf(z0, fmaxf(z1, z2));
    float e0 = expf(z0 - mz), e1 = expf(z1 - mz), e2 = expf(z2 - mz);
    float sd = e0 + e1 + e2;
    float wm[3] = { e0 / sd, e1 / sd, e2 / sd };
    for (int f = 0; f < 3; f++) { o_w[f] = wm[f]; wmeta[f] = wm[f]; }
    float c9[9];
    for (int f = 0; f < 3; f++)
      for (int n = 0; n < 3; n++) {
        c9[f * 3 + n] = wm[f] * wbub[f * 3 + n];
        coeff[f * 3 + n] = c9[f * 3 + n];
      }
    // M_ij = sqrt(c_i c_j) * (u_i . u_j) : same nonzero spectrum as rho_meta
    float M[81];
    {
      int p = 0;
      for (int i = 0; i < 9; i++)
        for (int j = i; j < 9; j++) {
          float val = sqrtf(c9[i] * c9[j]) * G[p];
          M[i * 9 + j] = val; M[j * 9 + i] = val;
          p++;
        }
    }
    // cyclic Jacobi eigenvalues
    for (int sweep = 0; sweep < 8; sweep++) {
      float off = 0.f;
      for (int i = 0; i < 9; i++)
        for (int j = i + 1; j < 9; j++) off += M[i * 9 + j] * M[i * 9 + j];
      if (off < 1e-22f) break;
      for (int p = 0; p < 8; p++)
        for (int q = p + 1; q < 9; q++) {
          float apq = M[p * 9 + q];
          if (fabsf(apq) < 1e-20f) continue;
          float app = M[p * 9 + p], aqq = M[q * 9 + q];
          float theta = 0.5f * (aqq - app) / apq;
          float tt = ((theta >= 0.f) ? 1.f : -1.f) / (fabsf(theta) + sqrtf(theta * theta + 1.f));
          float cc = 1.f / sqrtf(tt * tt + 1.f);
          float ssn = tt * cc;
          for (int k = 0; k < 9; k++) {
            float mpk = M[p * 9 + k], mqk = M[q * 9 + k];
            M[p * 9 + k] = cc * mpk - ssn * mqk;
            M[q * 9 + k] = ssn * mpk + cc * mqk;
          }
          for (int k = 0; k < 9; k++) {
            float mkp = M[k * 9 + p], mkq = M[k * 9 + q];
            M[k * 9 + p] = cc * mkp - ssn * mkq;
            M[k * 9 + q] = ssn * mkp + cc * mkq;
          }
        }
    }
    float total = 503.0f * 1e-12f;   // 512-9 eigenvalues clipped to 1e-12
    float ev[9];
    for (int k = 0; k < 9; k++) { ev[k] = fmaxf(M[k * 9 + k], 1e-12f); total += ev[k]; }
    float S = 0.f;
    for (int k = 0; k < 9; k++) {
      float q = ev[k] / total;
      S -= q * fmaxf(logf(q), -100.0f);
    }
    float q0 = 1e-12f / total;
    S -= 503.0f * (q0 * fmaxf(logf(q0), -100.0f));
    o_sr[0] = S; srho_ws[0] = S;
  }
}

// rho_meta[i][j] = sum_k c_k u_k[i] u_k[j]
__global__ void k_rho(const float* __restrict__ normed, const float* __restrict__ coeff,
                      float* __restrict__ rho) {
  const int i = blockIdx.x, tid = threadIdx.x;   // 512 blocks x 256
  __shared__ float cr[9];
  if (tid < 9) cr[tid] = coeff[tid] * normed[tid * DD + i];
  __syncthreads();
  for (int j = tid; j < DD; j += 256) {
    float s = 0.f;
#pragma unroll
    for (int k = 0; k < 9; k++) s += cr[k] * normed[k * DD + j];
    rho[i * DD + j] = s;
  }
}

// token_probs = softmax(sum_f w_f log dist_f), H_tok, F
__global__ void k_tok(const float* __restrict__ dist, const float* __restrict__ wmeta,
                      const float* __restrict__ logSArr, const float* __restrict__ srho,
                      float* __restrict__ o_tok, float* __restrict__ o_h,
                      float* __restrict__ o_f) {
  const int tid = threadIdx.x;   // 1024 threads
  __shared__ float red[16];
  __shared__ float sw[6];
  if (tid < 3) { sw[tid] = wmeta[tid]; sw[3 + tid] = logSArr[tid]; }
  __syncthreads();
  const float w0 = sw[0], w1 = sw[1], w2 = sw[2];
  // tight upper bound: s_v <= -sum_f w_f logS_f (since max dist_f = 1/S_f)
  const float shift = -(w0 * sw[3] + w1 * sw[4] + w2 * sw[5]);
  const float* A = dist;
  const float* B = dist + VOCAB;
  const float* C = dist + 2 * VOCAB;
  float se = 0.f;
  for (int v = tid; v < VOCAB; v += blockDim.x) {
    float s = w0 * logf(A[v]) + w1 * logf(B[v]) + w2 * logf(C[v]);
    se += expf(s - shift);
  }
  float S = blockReduceSum(se, red);
  float lgS = logf(S);
  float pl = 0.f;
  for (int v = tid; v < VOCAB; v += blockDim.x) {
    float s = w0 * logf(A[v]) + w1 * logf(B[v]) + w2 * logf(C[v]);
    float t = s - shift - lgS;
    float p = expf(t);
    o_tok[v] = p;
    pl += p * fmaxf(t, -100.0f);
  }
  float spl = blockReduceSum(pl, red);
  if (tid == 0) {
    float H = -spl;
    o_h[0] = H;
    o_f[0] = H - srho[0];
  }
}

// ---------------- host launcher ----------------
extern "C" void kernel_launch(void* const* d_in, const int* in_sizes, int n_in,
                              void* d_out, int out_size, void* d_ws, size_t ws_size,
                              hipStream_t stream) {
  const int*   tokens = (const int*)d_in[0];
  const float* E      = (const float*)d_in[1];
  const float* Ws     = (const float*)d_in[2];
  const float* temp_p = (const float*)d_in[3];
  const float* base_p = (const float*)d_in[4];
  const float* sens_p = (const float*)d_in[5];

  float* out   = (float*)d_out;
  float* o_tok = out;                       // [4][32768]
  float* o_rho = o_tok + SEQ * VOCAB;       // [4][512][512]
  float* o_w   = o_rho + (size_t)SEQ * DD * DD;  // [4][3]
  float* o_sr  = o_w + SEQ * NF;            // [4]
  float* o_h   = o_sr + SEQ;                // [4]
  float* o_f   = o_h + SEQ;                 // [4]
  float* o_d   = o_f + SEQ;                 // [4][3][32768]

  float* ws       = (float*)d_ws;
  float* w_mem    = ws;            // 4608
  float* w_xin    = ws + 4608;     // 1536
  float* w_decay  = ws + 6144;     // 3
  float* w_states = ws + 6656;     // 4608
  float* w_normed = ws + 11264;    // 4608 (16B-aligned offset)
  float* w_wbub   = ws + 15872;    // 9
  int*   w_bmax   = (int*)(ws + 15884);  // 3
  float* w_conc   = ws + 15888;    // 3
  float* w_sumsq  = ws + 15892;    // 3
  float* w_cross  = ws + 15896;    // 3
  float* w_wmeta  = ws + 15900;    // 3
  float* w_coeff  = ws + 15904;    // 9
  float* w_srho   = ws + 15916;    // 1
  float* w_logS   = ws + 15920;    // 3

  k_zero<<<18, 256, 0, stream>>>(w_mem, NF * NB * DD);

  for (int t = 0; t < SEQ; t++) {
    float* dists_t = o_d + (size_t)t * NF * VOCAB;
    k_pre<<<NF, 256, 0, stream>>>(tokens, E, w_mem, w_xin, w_decay, base_p, sens_p, t);
    k_states<<<dim3(NF * NB, 4), 128, 0, stream>>>(Ws, w_xin, w_states);
    k_equil<<<NF, 256, 0, stream>>>(w_states, w_mem, w_normed, w_wbub, w_decay, w_bmax);
    k_born<<<2048, 256, 0, stream>>>((const float4*)E, (const float4*)w_normed,
                                     w_wbub, dists_t, w_bmax);
    k_softmax<<<NF, 1024, 0, stream>>>(dists_t, w_bmax, w_conc, w_sumsq, w_logS);
    k_cross<<<3, 1024, 0, stream>>>(dists_t, w_cross);
    k_meta<<<1, 256, 0, stream>>>(w_normed, w_wbub, w_conc, w_sumsq, w_cross, temp_p,
                                  o_w + t * NF, o_sr + t, w_wmeta, w_coeff, w_srho);
    k_rho<<<DD, 256, 0, stream>>>(w_normed, w_coeff, o_rho + (size_t)t * DD * DD);
    k_tok<<<1, 1024, 0, stream>>>(dists_t, w_wmeta, w_logS, w_srho,
                                  o_tok + (size_t)t * VOCAB, o_h + t, o_f + t);
  }
}

// Round 2
// 1187.029 us; speedup vs baseline: 1.0776x; 1.0776x over previous
//
#include <hip/hip_runtime.h>
#include <math.h>

#define VOCAB 32768
#define DD 512
#define NB 3
#define NF 3
#define SEQ 4
#define MAX_ENT_F 10.3972077083991790f

// pair index tables for i<=j over 9 (45 pairs)
__device__ const unsigned char PI9[45] = {
  0,0,0,0,0,0,0,0,0, 1,1,1,1,1,1,1,1, 2,2,2,2,2,2,2, 3,3,3,3,3,3,
  4,4,4,4,4, 5,5,5,5, 6,6,6, 7,7, 8};
__device__ const unsigned char PJ9[45] = {
  0,1,2,3,4,5,6,7,8, 1,2,3,4,5,6,7,8, 2,3,4,5,6,7,8, 3,4,5,6,7,8,
  4,5,6,7,8, 5,6,7,8, 6,7,8, 7,8, 8};

// ---------------- reduction helpers ----------------
__device__ __forceinline__ float blockReduceSum(float v, float* sh) {
  int lane = threadIdx.x & 63;
  int wid  = threadIdx.x >> 6;
#pragma unroll
  for (int off = 32; off; off >>= 1) v += __shfl_down(v, off, 64);
  __syncthreads();                    // protect sh reuse across calls
  if (lane == 0) sh[wid] = v;
  __syncthreads();
  int nw = blockDim.x >> 6;
  float r = 0.0f;
  if ((int)threadIdx.x < nw) r = sh[threadIdx.x];
  if (wid == 0) {
#pragma unroll
    for (int off = 8; off; off >>= 1) r += __shfl_down(r, off, 64);
    if (lane == 0) sh[0] = r;
  }
  __syncthreads();
  return sh[0];
}

// ---------------- kernels ----------------
__global__ void k_zero(float* p, int n) {
  int i = blockIdx.x * blockDim.x + threadIdx.x;
  if (i < n) p[i] = 0.0f;
}

// per-foam: mem_mean, novelty, decay, xin = x + decay*mem_mean
__global__ void k_pre(const int* __restrict__ tokens, const float* __restrict__ E,
                      const float* __restrict__ mem, float* __restrict__ xin,
                      float* __restrict__ decayArr, const float* __restrict__ base_p,
                      const float* __restrict__ sens_p, int t) {
  const int f = blockIdx.x, tid = threadIdx.x;     // 256 threads
  __shared__ float smean[DD];
  __shared__ float red[16];
  __shared__ float s_decay;
  const float* x = E + (size_t)tokens[t] * DD;
  const float* m = mem + f * (NB * DD);
  for (int d = tid; d < DD; d += 256)
    smean[d] = (m[d] + m[DD + d] + m[2 * DD + d]) * (1.0f / 3.0f);
  __syncthreads();
  float pxm = 0.f, pxx = 0.f, pmm = 0.f;
  for (int d = tid; d < DD; d += 256) {
    float xv = x[d], mv = smean[d];
    pxm += xv * mv; pxx += xv * xv; pmm += mv * mv;
  }
  float sxm = blockReduceSum(pxm, red);
  float sxx = blockReduceSum(pxx, red);
  float smm = blockReduceSum(pmm, red);
  if (tid == 0) {
    float mem_norm = sqrtf(smm) + 1e-10f;
    float x_norm   = sqrtf(sxx) + 1e-10f;
    float novelty  = (mem_norm > 1e-8f) ? (1.0f - sxm / (x_norm * mem_norm)) : 1.0f;
    float sens = fabsf(sens_p[0]);
    float z = base_p[0] - sens * novelty;
    float dec = 1.0f / (1.0f + expf(-z));
    decayArr[f] = dec;
    s_decay = dec;
  }
  __syncthreads();
  float dec = s_decay;
  for (int d = tid; d < DD; d += 256)
    xin[f * DD + d] = x[d] + dec * smean[d];
}

// states[f][n][e] = sum_d xin[f][d] * Ws[f][n][d][e]
__global__ void k_states(const float* __restrict__ Ws, const float* __restrict__ xin,
                         float* __restrict__ states) {
  const int fn = blockIdx.x;             // 0..8
  const int f = fn / NB;
  const int e = blockIdx.y * 128 + threadIdx.x;
  __shared__ float sx[DD];
  for (int d = threadIdx.x; d < DD; d += 128) sx[d] = xin[f * DD + d];
  __syncthreads();
  const float* W = Ws + (size_t)fn * DD * DD + e;
  float acc = 0.f;
#pragma unroll 8
  for (int d = 0; d < DD; d++) acc += sx[d] * W[(size_t)d * DD];
  states[fn * DD + e] = acc;
}

// equilibrate, norms, bubble weights, normed, memory update, bmax init
__global__ void k_equil(const float* __restrict__ states, float* __restrict__ mem,
                        float* __restrict__ normed, float* __restrict__ wbub,
                        const float* __restrict__ decayArr, int* __restrict__ bmaxI) {
  const int f = blockIdx.x, tid = threadIdx.x;   // 256 threads
  __shared__ float s[NB * DD];
  __shared__ float red[16];
  __shared__ float snrm[NB];
  for (int i = tid; i < NB * DD; i += 256) s[i] = states[f * NB * DD + i];
  __syncthreads();
  for (int e = tid; e < DD; e += 256) {
    float a = s[e], b = s[DD + e], c = s[2 * DD + e];
#pragma unroll
    for (int it = 0; it < 3; it++) {
      float mn = (a + b + c) * (1.0f / 3.0f);
      a += 0.3f * (mn - a);
      b += 0.3f * (mn - b);
      c += 0.3f * (mn - c);
    }
    s[e] = a; s[DD + e] = b; s[2 * DD + e] = c;
  }
  __syncthreads();
  for (int n = 0; n < NB; n++) {
    float p = 0.f;
    for (int e = tid; e < DD; e += 256) { float v = s[n * DD + e]; p += v * v; }
    float ss = blockReduceSum(p, red);
    if (tid == 0) snrm[n] = sqrtf(ss);
  }
  __syncthreads();
  if (tid == 0) {
    float n0 = snrm[0], n1 = snrm[1], n2 = snrm[2];
    float mx = fmaxf(2.0f * n0, fmaxf(2.0f * n1, 2.0f * n2));
    float e0 = expf(2.0f * n0 - mx), e1 = expf(2.0f * n1 - mx), e2 = expf(2.0f * n2 - mx);
    float sd = e0 + e1 + e2;
    wbub[f * NB + 0] = e0 / sd;
    wbub[f * NB + 1] = e1 / sd;
    wbub[f * NB + 2] = e2 / sd;
    bmaxI[f] = 0;   // born >= 0 so 0 is a safe lower bound
  }
  float dec = decayArr[f];
  for (int i = tid; i < NB * DD; i += 256) {
    int n = i >> 9;
    float sv = s[i];
    normed[f * NB * DD + i] = sv / (snrm[n] + 1e-10f);
    float old = mem[f * NB * DD + i];
    mem[f * NB * DD + i] = dec * old + (1.0f - dec) * sv;
  }
}

// born_f[v] = sum_n wbub[f][n] * (E_v . normed[f][n])^2 ; atomic max per foam
__global__ __launch_bounds__(256) void k_born(const float4* __restrict__ E4,
                                              const float4* __restrict__ N4,
                                              const float* __restrict__ wbub,
                                              float* __restrict__ born,
                                              int* __restrict__ bmaxI) {
  const int tid = threadIdx.x, lane = tid & 63, wave = tid >> 6;
  float4 nr0[9], nr1[9];
#pragma unroll
  for (int j = 0; j < 9; j++) {
    nr0[j] = N4[j * 128 + lane];
    nr1[j] = N4[j * 128 + 64 + lane];
  }
  __shared__ float w9[9];
  __shared__ float sb[3][4];
  if (tid < 9) w9[tid] = wbub[tid];
  __syncthreads();
  float bm0 = 0.f, bm1 = 0.f, bm2 = 0.f;
  const int vbase = blockIdx.x * 16 + wave * 4;
#pragma unroll
  for (int r = 0; r < 4; r++) {
    int v = vbase + r;
    float4 a0 = E4[v * 128 + lane];
    float4 a1 = E4[v * 128 + 64 + lane];
    float acc[9];
#pragma unroll
    for (int j = 0; j < 9; j++) {
      float4 p = nr0[j], q = nr1[j];
      acc[j] = a0.x * p.x + a0.y * p.y + a0.z * p.z + a0.w * p.w +
               a1.x * q.x + a1.y * q.y + a1.z * q.z + a1.w * q.w;
    }
#pragma unroll
    for (int j = 0; j < 9; j++) {
      float a = acc[j];
#pragma unroll
      for (int off = 32; off; off >>= 1) a += __shfl_down(a, off, 64);
      acc[j] = a;
    }
    if (lane == 0) {
      float b0 = w9[0] * acc[0] * acc[0] + w9[1] * acc[1] * acc[1] + w9[2] * acc[2] * acc[2];
      float b1 = w9[3] * acc[3] * acc[3] + w9[4] * acc[4] * acc[4] + w9[5] * acc[5] * acc[5];
      float b2 = w9[6] * acc[6] * acc[6] + w9[7] * acc[7] * acc[7] + w9[8] * acc[8] * acc[8];
      born[v] = b0; born[VOCAB + v] = b1; born[2 * VOCAB + v] = b2;
      bm0 = fmaxf(bm0, b0); bm1 = fmaxf(bm1, b1); bm2 = fmaxf(bm2, b2);
    }
  }
  if (lane == 0) { sb[0][wave] = bm0; sb[1][wave] = bm1; sb[2][wave] = bm2; }
  __syncthreads();
  if (tid < 3) {
    float m = fmaxf(fmaxf(sb[tid][0], sb[tid][1]), fmaxf(sb[tid][2], sb[tid][3]));
    atomicMax(&bmaxI[tid], __float_as_int(m));
  }
}

// per-foam softmax in place (born -> dists), entropy -> concentration, sum p^2, logS
__global__ void k_softmax(float* __restrict__ dist, const int* __restrict__ bmaxI,
                          float* __restrict__ conc, float* __restrict__ sumsq,
                          float* __restrict__ logSArr) {
  const int f = blockIdx.x, tid = threadIdx.x;   // 1024 threads
  __shared__ float red[16];
  const float bmax = __int_as_float(bmaxI[f]);
  float* arr = dist + f * VOCAB;
  float se = 0.f;
  for (int v = tid; v < VOCAB; v += blockDim.x) se += expf(arr[v] - bmax);
  float S = blockReduceSum(se, red);
  float lgS = logf(S);
  float pl = 0.f, sq = 0.f;
  for (int v = tid; v < VOCAB; v += blockDim.x) {
    float t = arr[v] - bmax - lgS;
    float p = expf(t);
    arr[v] = p;
    pl += p * fmaxf(t, -100.0f);
    sq += p * p;
  }
  float spl = blockReduceSum(pl, red);
  float ssq = blockReduceSum(sq, red);
  if (tid == 0) {
    conc[f] = 1.0f + spl / MAX_ENT_F;     // 1 - (-spl)/MAX_ENT
    sumsq[f] = ssq;
    logSArr[f] = lgS;
  }
}

// pairwise sums dist_a . dist_b for pairs (0,1),(0,2),(1,2)
__global__ void k_cross(const float* __restrict__ dist, float* __restrict__ cross) {
  const int p = blockIdx.x, tid = threadIdx.x;  // 1024 threads
  const int a = (p < 2) ? 0 : 1;
  const int b = (p == 0) ? 1 : 2;
  const float* A = dist + a * VOCAB;
  const float* B = dist + b * VOCAB;
  __shared__ float red[16];
  float s = 0.f;
  for (int v = tid; v < VOCAB; v += blockDim.x) s += A[v] * B[v];
  float t = blockReduceSum(s, red);
  if (tid == 0) cross[p] = t;
}

// meta weights, coefficients, 9x9 spectrum -> S_rho
// G (45 Gram entries) computed pair-parallel; Jacobi fully register-resident
// on thread 0 (rotation body unrolled w/ constant indices -> SROA to VGPRs).
__global__ __launch_bounds__(512) void k_meta(
                       const float* __restrict__ normed, const float* __restrict__ wbub,
                       const float* __restrict__ conc, const float* __restrict__ sumsq,
                       const float* __restrict__ cross, const float* __restrict__ temp_p,
                       float* __restrict__ o_w, float* __restrict__ o_sr,
                       float* __restrict__ wmeta, float* __restrict__ coeff,
                       float* __restrict__ srho_ws) {
  const int tid = threadIdx.x;   // 512 threads
  __shared__ float G[45];
  // ---- Gram: pair p handled by 8 lanes ----
  const int p = tid >> 3, sub = tid & 7;
  if (p < 45) {
    const float4* ni = (const float4*)(normed + (int)PI9[p] * DD);
    const float4* nj = (const float4*)(normed + (int)PJ9[p] * DD);
    float s = 0.f;
#pragma unroll
    for (int it = 0; it < 16; it++) {
      float4 a = ni[sub * 16 + it];
      float4 b = nj[sub * 16 + it];
      s += a.x * b.x + a.y * b.y + a.z * b.z + a.w * b.w;
    }
    s += __shfl_down(s, 4, 8);
    s += __shfl_down(s, 2, 8);
    s += __shfl_down(s, 1, 8);
    if (sub == 0) G[p] = s;
  }
  __syncthreads();
  if (tid == 0) {
    float np0 = sqrtf(sumsq[0]) + 1e-10f;
    float np1 = sqrtf(sumsq[1]) + 1e-10f;
    float np2 = sqrtf(sumsq[2]) + 1e-10f;
    float A01 = cross[0] / (np0 * np1);
    float A02 = cross[1] / (np0 * np2);
    float A12 = cross[2] / (np1 * np2);
    float ag0 = 0.5f * (A01 + A02);
    float ag1 = 0.5f * (A01 + A12);
    float ag2 = 0.5f * (A02 + A12);
    float temp = fmaxf(fabsf(temp_p[0]), 0.01f);
    float z0 = conc[0] * ag0 / temp, z1 = conc[1] * ag1 / temp, z2 = conc[2] * ag2 / temp;
    float mz = fmaxf(z0, fmaxf(z1, z2));
    float e0 = expf(z0 - mz), e1 = expf(z1 - mz), e2 = expf(z2 - mz);
    float sd = e0 + e1 + e2;
    float wm[3] = { e0 / sd, e1 / sd, e2 / sd };
#pragma unroll
    for (int f = 0; f < 3; f++) { o_w[f] = wm[f]; wmeta[f] = wm[f]; }
    float c9[9];
#pragma unroll
    for (int f = 0; f < 3; f++)
#pragma unroll
      for (int n = 0; n < 3; n++) {
        c9[f * 3 + n] = wm[f] * wbub[f * 3 + n];
        coeff[f * 3 + n] = c9[f * 3 + n];
      }
    float sq9[9];
#pragma unroll
    for (int i = 0; i < 9; i++) sq9[i] = sqrtf(c9[i]);
    // M_ij = sqrt(c_i c_j) * (u_i . u_j) : same nonzero spectrum as rho_meta
    float M[81];
#pragma unroll
    for (int i = 0; i < 9; i++)
#pragma unroll
      for (int j = i; j < 9; j++) {
        float val = sq9[i] * sq9[j] * G[i * (19 - i) / 2 + (j - i)];
        M[i * 9 + j] = val;
        M[j * 9 + i] = val;
      }
    // cyclic Jacobi, rotations unrolled (constant indices -> registers)
#pragma unroll 1
    for (int sweep = 0; sweep < 6; sweep++) {
#pragma unroll
      for (int pp = 0; pp < 8; pp++) {
#pragma unroll
        for (int q = pp + 1; q < 9; q++) {
          float apq = M[pp * 9 + q];
          float app = M[pp * 9 + pp], aqq = M[q * 9 + q];
          float denom = (fabsf(apq) > 1e-25f) ? apq : 1e-25f;
          float theta = 0.5f * (aqq - app) / denom;
          float tt = copysignf(1.0f, theta) / (fabsf(theta) + sqrtf(theta * theta + 1.f));
          float cc = 1.f / sqrtf(tt * tt + 1.f);
          float ssn = tt * cc;
#pragma unroll
          for (int k = 0; k < 9; k++) {
            float mpk = M[pp * 9 + k], mqk = M[q * 9 + k];
            M[pp * 9 + k] = cc * mpk - ssn * mqk;
            M[q * 9 + k]  = ssn * mpk + cc * mqk;
          }
#pragma unroll
          for (int k = 0; k < 9; k++) {
            float mkp = M[k * 9 + pp], mkq = M[k * 9 + q];
            M[k * 9 + pp] = cc * mkp - ssn * mkq;
            M[k * 9 + q]  = ssn * mkp + cc * mkq;
          }
        }
      }
    }
    float total = 503.0f * 1e-12f;   // 512-9 eigenvalues clipped to 1e-12
    float ev[9];
#pragma unroll
    for (int k = 0; k < 9; k++) { ev[k] = fmaxf(M[k * 9 + k], 1e-12f); total += ev[k]; }
    float S = 0.f;
#pragma unroll
    for (int k = 0; k < 9; k++) {
      float q = ev[k] / total;
      S -= q * fmaxf(logf(q), -100.0f);
    }
    float q0 = 1e-12f / total;
    S -= 503.0f * (q0 * fmaxf(logf(q0), -100.0f));
    o_sr[0] = S; srho_ws[0] = S;
  }
}

// rho_meta[i][j] = sum_k c_k u_k[i] u_k[j]
__global__ void k_rho(const float* __restrict__ normed, const float* __restrict__ coeff,
                      float* __restrict__ rho) {
  const int i = blockIdx.x, tid = threadIdx.x;   // 512 blocks x 256
  __shared__ float cr[9];
  if (tid < 9) cr[tid] = coeff[tid] * normed[tid * DD + i];
  __syncthreads();
  for (int j = tid; j < DD; j += 256) {
    float s = 0.f;
#pragma unroll
    for (int k = 0; k < 9; k++) s += cr[k] * normed[k * DD + j];
    rho[i * DD + j] = s;
  }
}

// token_probs = softmax(sum_f w_f log dist_f), H_tok, F
__global__ void k_tok(const float* __restrict__ dist, const float* __restrict__ wmeta,
                      const float* __restrict__ logSArr, const float* __restrict__ srho,
                      float* __restrict__ o_tok, float* __restrict__ o_h,
                      float* __restrict__ o_f) {
  const int tid = threadIdx.x;   // 1024 threads
  __shared__ float red[16];
  __shared__ float sw[6];
  if (tid < 3) { sw[tid] = wmeta[tid]; sw[3 + tid] = logSArr[tid]; }
  __syncthreads();
  const float w0 = sw[0], w1 = sw[1], w2 = sw[2];
  // tight upper bound: s_v <= -sum_f w_f logS_f (since max dist_f = 1/S_f)
  const float shift = -(w0 * sw[3] + w1 * sw[4] + w2 * sw[5]);
  const float* A = dist;
  const float* B = dist + VOCAB;
  const float* C = dist + 2 * VOCAB;
  float se = 0.f;
  for (int v = tid; v < VOCAB; v += blockDim.x) {
    float s = w0 * logf(A[v]) + w1 * logf(B[v]) + w2 * logf(C[v]);
    se += expf(s - shift);
  }
  float S = blockReduceSum(se, red);
  float lgS = logf(S);
  float pl = 0.f;
  for (int v = tid; v < VOCAB; v += blockDim.x) {
    float s = w0 * logf(A[v]) + w1 * logf(B[v]) + w2 * logf(C[v]);
    float t = s - shift - lgS;
    float p = expf(t);
    o_tok[v] = p;
    pl += p * fmaxf(t, -100.0f);
  }
  float spl = blockReduceSum(pl, red);
  if (tid == 0) {
    float H = -spl;
    o_h[0] = H;
    o_f[0] = H - srho[0];
  }
}

// ---------------- host launcher ----------------
extern "C" void kernel_launch(void* const* d_in, const int* in_sizes, int n_in,
                              void* d_out, int out_size, void* d_ws, size_t ws_size,
                              hipStream_t stream) {
  const int*   tokens = (const int*)d_in[0];
  const float* E      = (const float*)d_in[1];
  const float* Ws     = (const float*)d_in[2];
  const float* temp_p = (const float*)d_in[3];
  const float* base_p = (const float*)d_in[4];
  const float* sens_p = (const float*)d_in[5];

  float* out   = (float*)d_out;
  float* o_tok = out;                       // [4][32768]
  float* o_rho = o_tok + SEQ * VOCAB;       // [4][512][512]
  float* o_w   = o_rho + (size_t)SEQ * DD * DD;  // [4][3]
  float* o_sr  = o_w + SEQ * NF;            // [4]
  float* o_h   = o_sr + SEQ;                // [4]
  float* o_f   = o_h + SEQ;                 // [4]
  float* o_d   = o_f + SEQ;                 // [4][3][32768]

  float* ws       = (float*)d_ws;
  float* w_mem    = ws;            // 4608
  float* w_xin    = ws + 4608;     // 1536
  float* w_decay  = ws + 6144;     // 3
  float* w_states = ws + 6656;     // 4608
  float* w_normed = ws + 11264;    // 4608 (16B-aligned offset)
  float* w_wbub   = ws + 15872;    // 9
  int*   w_bmax   = (int*)(ws + 15884);  // 3
  float* w_conc   = ws + 15888;    // 3
  float* w_sumsq  = ws + 15892;    // 3
  float* w_cross  = ws + 15896;    // 3
  float* w_wmeta  = ws + 15900;    // 3
  float* w_coeff  = ws + 15904;    // 9
  float* w_srho   = ws + 15916;    // 1
  float* w_logS   = ws + 15920;    // 3

  k_zero<<<18, 256, 0, stream>>>(w_mem, NF * NB * DD);

  for (int t = 0; t < SEQ; t++) {
    float* dists_t = o_d + (size_t)t * NF * VOCAB;
    k_pre<<<NF, 256, 0, stream>>>(tokens, E, w_mem, w_xin, w_decay, base_p, sens_p, t);
    k_states<<<dim3(NF * NB, 4), 128, 0, stream>>>(Ws, w_xin, w_states);
    k_equil<<<NF, 256, 0, stream>>>(w_states, w_mem, w_normed, w_wbub, w_decay, w_bmax);
    k_born<<<2048, 256, 0, stream>>>((const float4*)E, (const float4*)w_normed,
                                     w_wbub, dists_t, w_bmax);
    k_softmax<<<NF, 1024, 0, stream>>>(dists_t, w_bmax, w_conc, w_sumsq, w_logS);
    k_cross<<<3, 1024, 0, stream>>>(dists_t, w_cross);
    k_meta<<<1, 512, 0, stream>>>(w_normed, w_wbub, w_conc, w_sumsq, w_cross, temp_p,
                                  o_w + t * NF, o_sr + t, w_wmeta, w_coeff, w_srho);
    k_rho<<<DD, 256, 0, stream>>>(w_normed, w_coeff, o_rho + (size_t)t * DD * DD);
    k_tok<<<1, 1024, 0, stream>>>(dists_t, w_wmeta, w_logS, w_srho,
                                  o_tok + (size_t)t * VOCAB, o_h + t, o_f + t);
  }
}

// Round 3
// 1132.403 us; speedup vs baseline: 1.1296x; 1.0482x over previous
//
#include <hip/hip_runtime.h>
#include <math.h>

#define VOCAB 32768
#define DD 512
#define NB 3
#define NF 3
#define SEQ 4
#define MAX_ENT_F 10.3972077083991790f

// pair index tables for i<=j over 9 (45 pairs)
__device__ const unsigned char PI9[45] = {
  0,0,0,0,0,0,0,0,0, 1,1,1,1,1,1,1,1, 2,2,2,2,2,2,2, 3,3,3,3,3,3,
  4,4,4,4,4, 5,5,5,5, 6,6,6, 7,7, 8};
__device__ const unsigned char PJ9[45] = {
  0,1,2,3,4,5,6,7,8, 1,2,3,4,5,6,7,8, 2,3,4,5,6,7,8, 3,4,5,6,7,8,
  4,5,6,7,8, 5,6,7,8, 6,7,8, 7,8, 8};

// ---------------- reduction helpers ----------------
__device__ __forceinline__ float blockReduceSum(float v, float* sh) {
  int lane = threadIdx.x & 63;
  int wid  = threadIdx.x >> 6;
#pragma unroll
  for (int off = 32; off; off >>= 1) v += __shfl_down(v, off, 64);
  __syncthreads();                    // protect sh reuse across calls
  if (lane == 0) sh[wid] = v;
  __syncthreads();
  int nw = blockDim.x >> 6;
  float r = 0.0f;
  if ((int)threadIdx.x < nw) r = sh[threadIdx.x];
  if (wid == 0) {
#pragma unroll
    for (int off = 8; off; off >>= 1) r += __shfl_down(r, off, 64);
    if (lane == 0) sh[0] = r;
  }
  __syncthreads();
  return sh[0];
}

// ---------------- kernels ----------------
__global__ void k_zero(float* p, int n) {
  int i = blockIdx.x * blockDim.x + threadIdx.x;
  if (i < n) p[i] = 0.0f;
}

// per-foam: mem_mean, novelty, decay, xin = x + decay*mem_mean
__global__ void k_pre(const int* __restrict__ tokens, const float* __restrict__ E,
                      const float* __restrict__ mem, float* __restrict__ xin,
                      float* __restrict__ decayArr, const float* __restrict__ base_p,
                      const float* __restrict__ sens_p, int t) {
  const int f = blockIdx.x, tid = threadIdx.x;     // 256 threads
  __shared__ float smean[DD];
  __shared__ float red[16];
  __shared__ float s_decay;
  const float* x = E + (size_t)tokens[t] * DD;
  const float* m = mem + f * (NB * DD);
  for (int d = tid; d < DD; d += 256)
    smean[d] = (m[d] + m[DD + d] + m[2 * DD + d]) * (1.0f / 3.0f);
  __syncthreads();
  float pxm = 0.f, pxx = 0.f, pmm = 0.f;
  for (int d = tid; d < DD; d += 256) {
    float xv = x[d], mv = smean[d];
    pxm += xv * mv; pxx += xv * xv; pmm += mv * mv;
  }
  float sxm = blockReduceSum(pxm, red);
  float sxx = blockReduceSum(pxx, red);
  float smm = blockReduceSum(pmm, red);
  if (tid == 0) {
    float mem_norm = sqrtf(smm) + 1e-10f;
    float x_norm   = sqrtf(sxx) + 1e-10f;
    float novelty  = (mem_norm > 1e-8f) ? (1.0f - sxm / (x_norm * mem_norm)) : 1.0f;
    float sens = fabsf(sens_p[0]);
    float z = base_p[0] - sens * novelty;
    float dec = 1.0f / (1.0f + expf(-z));
    decayArr[f] = dec;
    s_decay = dec;
  }
  __syncthreads();
  float dec = s_decay;
  for (int d = tid; d < DD; d += 256)
    xin[f * DD + d] = x[d] + dec * smean[d];
}

// states[f][n][e] = sum_d xin[f][d] * Ws[f][n][d][e]
__global__ void k_states(const float* __restrict__ Ws, const float* __restrict__ xin,
                         float* __restrict__ states) {
  const int fn = blockIdx.x;             // 0..8
  const int f = fn / NB;
  const int e = blockIdx.y * 128 + threadIdx.x;
  __shared__ float sx[DD];
  for (int d = threadIdx.x; d < DD; d += 128) sx[d] = xin[f * DD + d];
  __syncthreads();
  const float* W = Ws + (size_t)fn * DD * DD + e;
  float acc = 0.f;
#pragma unroll 8
  for (int d = 0; d < DD; d++) acc += sx[d] * W[(size_t)d * DD];
  states[fn * DD + e] = acc;
}

// equilibrate, norms, bubble weights, normed, memory update, bmax init
__global__ void k_equil(const float* __restrict__ states, float* __restrict__ mem,
                        float* __restrict__ normed, float* __restrict__ wbub,
                        const float* __restrict__ decayArr, int* __restrict__ bmaxI) {
  const int f = blockIdx.x, tid = threadIdx.x;   // 256 threads
  __shared__ float s[NB * DD];
  __shared__ float red[16];
  __shared__ float snrm[NB];
  for (int i = tid; i < NB * DD; i += 256) s[i] = states[f * NB * DD + i];
  __syncthreads();
  for (int e = tid; e < DD; e += 256) {
    float a = s[e], b = s[DD + e], c = s[2 * DD + e];
#pragma unroll
    for (int it = 0; it < 3; it++) {
      float mn = (a + b + c) * (1.0f / 3.0f);
      a += 0.3f * (mn - a);
      b += 0.3f * (mn - b);
      c += 0.3f * (mn - c);
    }
    s[e] = a; s[DD + e] = b; s[2 * DD + e] = c;
  }
  __syncthreads();
  for (int n = 0; n < NB; n++) {
    float p = 0.f;
    for (int e = tid; e < DD; e += 256) { float v = s[n * DD + e]; p += v * v; }
    float ss = blockReduceSum(p, red);
    if (tid == 0) snrm[n] = sqrtf(ss);
  }
  __syncthreads();
  if (tid == 0) {
    float n0 = snrm[0], n1 = snrm[1], n2 = snrm[2];
    float mx = fmaxf(2.0f * n0, fmaxf(2.0f * n1, 2.0f * n2));
    float e0 = expf(2.0f * n0 - mx), e1 = expf(2.0f * n1 - mx), e2 = expf(2.0f * n2 - mx);
    float sd = e0 + e1 + e2;
    wbub[f * NB + 0] = e0 / sd;
    wbub[f * NB + 1] = e1 / sd;
    wbub[f * NB + 2] = e2 / sd;
    bmaxI[f] = 0;   // born >= 0 so 0 is a safe lower bound
  }
  float dec = decayArr[f];
  for (int i = tid; i < NB * DD; i += 256) {
    int n = i >> 9;
    float sv = s[i];
    normed[f * NB * DD + i] = sv / (snrm[n] + 1e-10f);
    float old = mem[f * NB * DD + i];
    mem[f * NB * DD + i] = dec * old + (1.0f - dec) * sv;
  }
}

// born_f[v] = sum_n wbub[f][n] * (E_v . normed[f][n])^2 ; atomic max per foam
__global__ __launch_bounds__(256) void k_born(const float4* __restrict__ E4,
                                              const float4* __restrict__ N4,
                                              const float* __restrict__ wbub,
                                              float* __restrict__ born,
                                              int* __restrict__ bmaxI) {
  const int tid = threadIdx.x, lane = tid & 63, wave = tid >> 6;
  float4 nr0[9], nr1[9];
#pragma unroll
  for (int j = 0; j < 9; j++) {
    nr0[j] = N4[j * 128 + lane];
    nr1[j] = N4[j * 128 + 64 + lane];
  }
  __shared__ float w9[9];
  __shared__ float sb[3][4];
  if (tid < 9) w9[tid] = wbub[tid];
  __syncthreads();
  float bm0 = 0.f, bm1 = 0.f, bm2 = 0.f;
  const int vbase = blockIdx.x * 16 + wave * 4;
#pragma unroll
  for (int r = 0; r < 4; r++) {
    int v = vbase + r;
    float4 a0 = E4[v * 128 + lane];
    float4 a1 = E4[v * 128 + 64 + lane];
    float acc[9];
#pragma unroll
    for (int j = 0; j < 9; j++) {
      float4 p = nr0[j], q = nr1[j];
      acc[j] = a0.x * p.x + a0.y * p.y + a0.z * p.z + a0.w * p.w +
               a1.x * q.x + a1.y * q.y + a1.z * q.z + a1.w * q.w;
    }
#pragma unroll
    for (int j = 0; j < 9; j++) {
      float a = acc[j];
#pragma unroll
      for (int off = 32; off; off >>= 1) a += __shfl_down(a, off, 64);
      acc[j] = a;
    }
    if (lane == 0) {
      float b0 = w9[0] * acc[0] * acc[0] + w9[1] * acc[1] * acc[1] + w9[2] * acc[2] * acc[2];
      float b1 = w9[3] * acc[3] * acc[3] + w9[4] * acc[4] * acc[4] + w9[5] * acc[5] * acc[5];
      float b2 = w9[6] * acc[6] * acc[6] + w9[7] * acc[7] * acc[7] + w9[8] * acc[8] * acc[8];
      born[v] = b0; born[VOCAB + v] = b1; born[2 * VOCAB + v] = b2;
      bm0 = fmaxf(bm0, b0); bm1 = fmaxf(bm1, b1); bm2 = fmaxf(bm2, b2);
    }
  }
  if (lane == 0) { sb[0][wave] = bm0; sb[1][wave] = bm1; sb[2][wave] = bm2; }
  __syncthreads();
  if (tid < 3) {
    float m = fmaxf(fmaxf(sb[tid][0], sb[tid][1]), fmaxf(sb[tid][2], sb[tid][3]));
    atomicMax(&bmaxI[tid], __float_as_int(m));
  }
}

// per-foam softmax in place (born -> dists), entropy -> concentration, sum p^2, logS
__global__ void k_softmax(float* __restrict__ dist, const int* __restrict__ bmaxI,
                          float* __restrict__ conc, float* __restrict__ sumsq,
                          float* __restrict__ logSArr) {
  const int f = blockIdx.x, tid = threadIdx.x;   // 1024 threads
  __shared__ float red[16];
  const float bmax = __int_as_float(bmaxI[f]);
  float* arr = dist + f * VOCAB;
  float se = 0.f;
  for (int v = tid; v < VOCAB; v += blockDim.x) se += expf(arr[v] - bmax);
  float S = blockReduceSum(se, red);
  float lgS = logf(S);
  float pl = 0.f, sq = 0.f;
  for (int v = tid; v < VOCAB; v += blockDim.x) {
    float t = arr[v] - bmax - lgS;
    float p = expf(t);
    arr[v] = p;
    pl += p * fmaxf(t, -100.0f);
    sq += p * p;
  }
  float spl = blockReduceSum(pl, red);
  float ssq = blockReduceSum(sq, red);
  if (tid == 0) {
    conc[f] = 1.0f + spl / MAX_ENT_F;     // 1 - (-spl)/MAX_ENT
    sumsq[f] = ssq;
    logSArr[f] = lgS;
  }
}

// pairwise sums dist_a . dist_b for pairs (0,1),(0,2),(1,2)
__global__ void k_cross(const float* __restrict__ dist, float* __restrict__ cross) {
  const int p = blockIdx.x, tid = threadIdx.x;  // 1024 threads
  const int a = (p < 2) ? 0 : 1;
  const int b = (p == 0) ? 1 : 2;
  const float* A = dist + a * VOCAB;
  const float* B = dist + b * VOCAB;
  __shared__ float red[16];
  float s = 0.f;
  for (int v = tid; v < VOCAB; v += blockDim.x) s += A[v] * B[v];
  float t = blockReduceSum(s, red);
  if (tid == 0) cross[p] = t;
}

// Gram G[45] -> ws, meta weights, coefficients (NO Jacobi here)
__global__ __launch_bounds__(512) void k_meta_w(
                       const float* __restrict__ normed, const float* __restrict__ wbub,
                       const float* __restrict__ conc, const float* __restrict__ sumsq,
                       const float* __restrict__ cross, const float* __restrict__ temp_p,
                       float* __restrict__ o_w, float* __restrict__ wmeta,
                       float* __restrict__ coeff, float* __restrict__ Gout) {
  const int tid = threadIdx.x;   // 512 threads
  __shared__ float G[45];
  // ---- Gram: pair p handled by 8 lanes ----
  const int p = tid >> 3, sub = tid & 7;
  if (p < 45) {
    const float4* ni = (const float4*)(normed + (int)PI9[p] * DD);
    const float4* nj = (const float4*)(normed + (int)PJ9[p] * DD);
    float s = 0.f;
#pragma unroll
    for (int it = 0; it < 16; it++) {
      float4 a = ni[sub * 16 + it];
      float4 b = nj[sub * 16 + it];
      s += a.x * b.x + a.y * b.y + a.z * b.z + a.w * b.w;
    }
    s += __shfl_down(s, 4, 8);
    s += __shfl_down(s, 2, 8);
    s += __shfl_down(s, 1, 8);
    if (sub == 0) G[p] = s;
  }
  __syncthreads();
  if (tid < 45) Gout[tid] = G[tid];
  if (tid == 0) {
    float np0 = sqrtf(sumsq[0]) + 1e-10f;
    float np1 = sqrtf(sumsq[1]) + 1e-10f;
    float np2 = sqrtf(sumsq[2]) + 1e-10f;
    float A01 = cross[0] / (np0 * np1);
    float A02 = cross[1] / (np0 * np2);
    float A12 = cross[2] / (np1 * np2);
    float ag0 = 0.5f * (A01 + A02);
    float ag1 = 0.5f * (A01 + A12);
    float ag2 = 0.5f * (A02 + A12);
    float temp = fmaxf(fabsf(temp_p[0]), 0.01f);
    float z0 = conc[0] * ag0 / temp, z1 = conc[1] * ag1 / temp, z2 = conc[2] * ag2 / temp;
    float mz = fmaxf(z0, fmaxf(z1, z2));
    float e0 = expf(z0 - mz), e1 = expf(z1 - mz), e2 = expf(z2 - mz);
    float sd = e0 + e1 + e2;
    float wm[3] = { e0 / sd, e1 / sd, e2 / sd };
#pragma unroll
    for (int f = 0; f < 3; f++) { o_w[f] = wm[f]; wmeta[f] = wm[f]; }
#pragma unroll
    for (int f = 0; f < 3; f++)
#pragma unroll
      for (int n = 0; n < 3; n++)
        coeff[f * 3 + n] = wm[f] * wbub[f * 3 + n];
  }
}

// serial register-resident 9x9 Jacobi on thread 0 of a lone wave.
// __launch_bounds__(64,1): no VGPR cap pressure -> M[81] SROAs into VGPRs.
__global__ __launch_bounds__(64, 1) void k_jac(const float* __restrict__ Gg,
                                               const float* __restrict__ coeff,
                                               float* __restrict__ o_sr,
                                               float* __restrict__ srho_ws) {
  if (threadIdx.x != 0) return;
  float G[45];
#pragma unroll
  for (int i = 0; i < 45; i++) G[i] = Gg[i];
  float sq9[9];
#pragma unroll
  for (int i = 0; i < 9; i++) sq9[i] = sqrtf(coeff[i]);
  // M_ij = sqrt(c_i c_j) * (u_i . u_j) : same nonzero spectrum as rho_meta
  float M[81];
#pragma unroll
  for (int i = 0; i < 9; i++)
#pragma unroll
    for (int j = i; j < 9; j++) {
      float val = sq9[i] * sq9[j] * G[i * (19 - i) / 2 + (j - i)];
      M[i * 9 + j] = val;
      M[j * 9 + i] = val;
    }
  // cyclic Jacobi, rotations unrolled (constant indices -> registers)
#pragma unroll 1
  for (int sweep = 0; sweep < 5; sweep++) {
#pragma unroll
    for (int pp = 0; pp < 8; pp++) {
#pragma unroll
      for (int q = pp + 1; q < 9; q++) {
        float apq = M[pp * 9 + q];
        float app = M[pp * 9 + pp], aqq = M[q * 9 + q];
        float denom = (fabsf(apq) > 1e-25f) ? apq : 1e-25f;
        float theta = 0.5f * (aqq - app) / denom;
        float tt = copysignf(1.0f, theta) / (fabsf(theta) + sqrtf(theta * theta + 1.f));
        float cc = 1.f / sqrtf(tt * tt + 1.f);
        float ssn = tt * cc;
#pragma unroll
        for (int k = 0; k < 9; k++) {
          float mpk = M[pp * 9 + k], mqk = M[q * 9 + k];
          M[pp * 9 + k] = cc * mpk - ssn * mqk;
          M[q * 9 + k]  = ssn * mpk + cc * mqk;
        }
#pragma unroll
        for (int k = 0; k < 9; k++) {
          float mkp = M[k * 9 + pp], mkq = M[k * 9 + q];
          M[k * 9 + pp] = cc * mkp - ssn * mkq;
          M[k * 9 + q]  = ssn * mkp + cc * mkq;
        }
      }
    }
  }
  float total = 503.0f * 1e-12f;   // 512-9 eigenvalues clipped to 1e-12
  float ev[9];
#pragma unroll
  for (int k = 0; k < 9; k++) { ev[k] = fmaxf(M[k * 9 + k], 1e-12f); total += ev[k]; }
  float S = 0.f;
#pragma unroll
  for (int k = 0; k < 9; k++) {
    float q = ev[k] / total;
    S -= q * fmaxf(logf(q), -100.0f);
  }
  float q0 = 1e-12f / total;
  S -= 503.0f * (q0 * fmaxf(logf(q0), -100.0f));
  o_sr[0] = S; srho_ws[0] = S;
}

// rho_meta[i][j] = sum_k c_k u_k[i] u_k[j]
__global__ void k_rho(const float* __restrict__ normed, const float* __restrict__ coeff,
                      float* __restrict__ rho) {
  const int i = blockIdx.x, tid = threadIdx.x;   // 512 blocks x 256
  __shared__ float cr[9];
  if (tid < 9) cr[tid] = coeff[tid] * normed[tid * DD + i];
  __syncthreads();
  for (int j = tid; j < DD; j += 256) {
    float s = 0.f;
#pragma unroll
    for (int k = 0; k < 9; k++) s += cr[k] * normed[k * DD + j];
    rho[i * DD + j] = s;
  }
}

// token_probs = softmax(sum_f w_f log dist_f), H_tok, F
__global__ void k_tok(const float* __restrict__ dist, const float* __restrict__ wmeta,
                      const float* __restrict__ logSArr, const float* __restrict__ srho,
                      float* __restrict__ o_tok, float* __restrict__ o_h,
                      float* __restrict__ o_f) {
  const int tid = threadIdx.x;   // 1024 threads
  __shared__ float red[16];
  __shared__ float sw[6];
  if (tid < 3) { sw[tid] = wmeta[tid]; sw[3 + tid] = logSArr[tid]; }
  __syncthreads();
  const float w0 = sw[0], w1 = sw[1], w2 = sw[2];
  // tight upper bound: s_v <= -sum_f w_f logS_f (since max dist_f = 1/S_f)
  const float shift = -(w0 * sw[3] + w1 * sw[4] + w2 * sw[5]);
  const float* A = dist;
  const float* B = dist + VOCAB;
  const float* C = dist + 2 * VOCAB;
  float se = 0.f;
  for (int v = tid; v < VOCAB; v += blockDim.x) {
    float s = w0 * logf(A[v]) + w1 * logf(B[v]) + w2 * logf(C[v]);
    se += expf(s - shift);
  }
  float S = blockReduceSum(se, red);
  float lgS = logf(S);
  float pl = 0.f;
  for (int v = tid; v < VOCAB; v += blockDim.x) {
    float s = w0 * logf(A[v]) + w1 * logf(B[v]) + w2 * logf(C[v]);
    float t = s - shift - lgS;
    float p = expf(t);
    o_tok[v] = p;
    pl += p * fmaxf(t, -100.0f);
  }
  float spl = blockReduceSum(pl, red);
  if (tid == 0) {
    float H = -spl;
    o_h[0] = H;
    o_f[0] = H - srho[0];
  }
}

// ---------------- host launcher ----------------
extern "C" void kernel_launch(void* const* d_in, const int* in_sizes, int n_in,
                              void* d_out, int out_size, void* d_ws, size_t ws_size,
                              hipStream_t stream) {
  const int*   tokens = (const int*)d_in[0];
  const float* E      = (const float*)d_in[1];
  const float* Ws     = (const float*)d_in[2];
  const float* temp_p = (const float*)d_in[3];
  const float* base_p = (const float*)d_in[4];
  const float* sens_p = (const float*)d_in[5];

  float* out   = (float*)d_out;
  float* o_tok = out;                       // [4][32768]
  float* o_rho = o_tok + SEQ * VOCAB;       // [4][512][512]
  float* o_w   = o_rho + (size_t)SEQ * DD * DD;  // [4][3]
  float* o_sr  = o_w + SEQ * NF;            // [4]
  float* o_h   = o_sr + SEQ;                // [4]
  float* o_f   = o_h + SEQ;                 // [4]
  float* o_d   = o_f + SEQ;                 // [4][3][32768]

  float* ws       = (float*)d_ws;
  float* w_mem    = ws;            // 4608
  float* w_xin    = ws + 4608;     // 1536
  float* w_decay  = ws + 6144;     // 3
  float* w_states = ws + 6656;     // 4608
  float* w_normed = ws + 11264;    // 4608 (16B-aligned offset)
  float* w_wbub   = ws + 15872;    // 9
  int*   w_bmax   = (int*)(ws + 15884);  // 3
  float* w_conc   = ws + 15888;    // 3
  float* w_sumsq  = ws + 15892;    // 3
  float* w_cross  = ws + 15896;    // 3
  float* w_wmeta  = ws + 15900;    // 3
  float* w_coeff  = ws + 15904;    // 9
  float* w_srho   = ws + 15916;    // 1
  float* w_logS   = ws + 15920;    // 3
  float* w_G      = ws + 15936;    // 45

  k_zero<<<18, 256, 0, stream>>>(w_mem, NF * NB * DD);

  for (int t = 0; t < SEQ; t++) {
    float* dists_t = o_d + (size_t)t * NF * VOCAB;
    k_pre<<<NF, 256, 0, stream>>>(tokens, E, w_mem, w_xin, w_decay, base_p, sens_p, t);
    k_states<<<dim3(NF * NB, 4), 128, 0, stream>>>(Ws, w_xin, w_states);
    k_equil<<<NF, 256, 0, stream>>>(w_states, w_mem, w_normed, w_wbub, w_decay, w_bmax);
    k_born<<<2048, 256, 0, stream>>>((const float4*)E, (const float4*)w_normed,
                                     w_wbub, dists_t, w_bmax);
    k_softmax<<<NF, 1024, 0, stream>>>(dists_t, w_bmax, w_conc, w_sumsq, w_logS);
    k_cross<<<3, 1024, 0, stream>>>(dists_t, w_cross);
    k_meta_w<<<1, 512, 0, stream>>>(w_normed, w_wbub, w_conc, w_sumsq, w_cross, temp_p,
                                    o_w + t * NF, w_wmeta, w_coeff, w_G);
    k_jac<<<1, 64, 0, stream>>>(w_G, w_coeff, o_sr + t, w_srho);
    k_rho<<<DD, 256, 0, stream>>>(w_normed, w_coeff, o_rho + (size_t)t * DD * DD);
    k_tok<<<1, 1024, 0, stream>>>(dists_t, w_wmeta, w_logS, w_srho,
                                  o_tok + (size_t)t * VOCAB, o_h + t, o_f + t);
  }
}

// Round 4
// 966.046 us; speedup vs baseline: 1.3241x; 1.1722x over previous
//
#include <hip/hip_runtime.h>
#include <math.h>

#define VOCAB 32768
#define DD 512
#define NB 3
#define NF 3
#define SEQ 4
#define MAX_ENT_F 10.3972077083991790f

// scratch layout inside o_rho[t] (262144 floats, dead until k_rho_tok):
#define SCR_ST   0        // [9][8][512] states partials = 36864
#define SCR_PART 36864    // [12][2048] born-moment partials = 24576
#define SCR_G    61440    // [45] Gram
#define SCR_BORN 65536    // [3][VOCAB] = 98304

// pair index tables for i<=j over 9 (45 pairs)
__device__ const unsigned char PI9[45] = {
  0,0,0,0,0,0,0,0,0, 1,1,1,1,1,1,1,1, 2,2,2,2,2,2,2, 3,3,3,3,3,3,
  4,4,4,4,4, 5,5,5,5, 6,6,6, 7,7, 8};
__device__ const unsigned char PJ9[45] = {
  0,1,2,3,4,5,6,7,8, 1,2,3,4,5,6,7,8, 2,3,4,5,6,7,8, 3,4,5,6,7,8,
  4,5,6,7,8, 5,6,7,8, 6,7,8, 7,8, 8};

__device__ __forceinline__ float blockReduceSum(float v, float* sh) {
  int lane = threadIdx.x & 63;
  int wid  = threadIdx.x >> 6;
#pragma unroll
  for (int off = 32; off; off >>= 1) v += __shfl_down(v, off, 64);
  __syncthreads();
  if (lane == 0) sh[wid] = v;
  __syncthreads();
  int nw = blockDim.x >> 6;
  float r = 0.0f;
  if ((int)threadIdx.x < nw) r = sh[threadIdx.x];
  if (wid == 0) {
#pragma unroll
    for (int off = 8; off; off >>= 1) r += __shfl_down(r, off, 64);
    if (lane == 0) sh[0] = r;
  }
  __syncthreads();
  return sh[0];
}

__global__ void k_zero(float* p, int n) {
  int i = blockIdx.x * blockDim.x + threadIdx.x;
  if (i < n) p[i] = 0.0f;
}

// pre (redundant per block) + states K-chunk GEMV partials.
// grid (9, 8): fn = f*3+n, dc = K-chunk. 256 threads.
__global__ void k_states(const int* __restrict__ tokens, const float* __restrict__ E,
                         const float* __restrict__ mem, const float* __restrict__ Ws,
                         const float* __restrict__ base_p, const float* __restrict__ sens_p,
                         float* __restrict__ decayArr, float* __restrict__ scr_st, int t) {
  const int fn = blockIdx.x, dc = blockIdx.y, tid = threadIdx.x;
  const int f = fn / NB;
  const int d0 = dc * 64;
  __shared__ float smean[DD];
  __shared__ float xin_loc[64];
  __shared__ float red[16];
  __shared__ float s_decay;
  const float* x = E + (size_t)tokens[t] * DD;
  const float* m = mem + f * (NB * DD);
  for (int d = tid; d < DD; d += 256)
    smean[d] = (m[d] + m[DD + d] + m[2 * DD + d]) * (1.0f / 3.0f);
  __syncthreads();
  float pxm = 0.f, pxx = 0.f, pmm = 0.f;
  for (int d = tid; d < DD; d += 256) {
    float xv = x[d], mv = smean[d];
    pxm += xv * mv; pxx += xv * xv; pmm += mv * mv;
  }
  float sxm = blockReduceSum(pxm, red);
  float sxx = blockReduceSum(pxx, red);
  float smm = blockReduceSum(pmm, red);
  if (tid == 0) {
    float mem_norm = sqrtf(smm) + 1e-10f;
    float x_norm   = sqrtf(sxx) + 1e-10f;
    float novelty  = (mem_norm > 1e-8f) ? (1.0f - sxm / (x_norm * mem_norm)) : 1.0f;
    float sens = fabsf(sens_p[0]);
    float z = base_p[0] - sens * novelty;
    float dec = 1.0f / (1.0f + expf(-z));
    if (dc == 0 && fn % NB == 0) decayArr[f] = dec;
    s_decay = dec;
  }
  __syncthreads();
  if (tid < 64) xin_loc[tid] = x[d0 + tid] + s_decay * smean[d0 + tid];
  __syncthreads();
  const float* W = Ws + (size_t)fn * DD * DD + (size_t)d0 * DD;
  float acc0 = 0.f, acc1 = 0.f;
#pragma unroll 8
  for (int dd = 0; dd < 64; dd++) {
    float xv = xin_loc[dd];
    acc0 += xv * W[dd * DD + tid];
    acc1 += xv * W[dd * DD + tid + 256];
  }
  float* o = scr_st + (fn * 8 + dc) * DD;
  o[tid] = acc0;
  o[tid + 256] = acc1;
}

// sum K-chunks, equilibrate, norms, bubble weights, normed, memory update
__global__ void k_equil(const float* __restrict__ scr_st, float* __restrict__ mem,
                        float* __restrict__ normed, float* __restrict__ wbub,
                        const float* __restrict__ decayArr) {
  const int f = blockIdx.x, tid = threadIdx.x;   // 256 threads
  __shared__ float s[NB * DD];
  __shared__ float red[16];
  __shared__ float snrm[NB];
  for (int i = tid; i < NB * DD; i += 256) {
    int n = i >> 9, e = i & 511;
    const float* src = scr_st + ((f * NB + n) * 8) * DD + e;
    float acc = 0.f;
#pragma unroll
    for (int dc = 0; dc < 8; dc++) acc += src[dc * DD];
    s[i] = acc;
  }
  __syncthreads();
  for (int e = tid; e < DD; e += 256) {
    float a = s[e], b = s[DD + e], c = s[2 * DD + e];
#pragma unroll
    for (int it = 0; it < 3; it++) {
      float mn = (a + b + c) * (1.0f / 3.0f);
      a += 0.3f * (mn - a);
      b += 0.3f * (mn - b);
      c += 0.3f * (mn - c);
    }
    s[e] = a; s[DD + e] = b; s[2 * DD + e] = c;
  }
  __syncthreads();
  for (int n = 0; n < NB; n++) {
    float p = 0.f;
    for (int e = tid; e < DD; e += 256) { float v = s[n * DD + e]; p += v * v; }
    float ss = blockReduceSum(p, red);
    if (tid == 0) snrm[n] = sqrtf(ss);
  }
  __syncthreads();
  if (tid == 0) {
    float n0 = snrm[0], n1 = snrm[1], n2 = snrm[2];
    float mx = fmaxf(2.0f * n0, fmaxf(2.0f * n1, 2.0f * n2));
    float e0 = expf(2.0f * n0 - mx), e1 = expf(2.0f * n1 - mx), e2 = expf(2.0f * n2 - mx);
    float sd = e0 + e1 + e2;
    wbub[f * NB + 0] = e0 / sd;
    wbub[f * NB + 1] = e1 / sd;
    wbub[f * NB + 2] = e2 / sd;
  }
  float dec = decayArr[f];
  for (int i = tid; i < NB * DD; i += 256) {
    int n = i >> 9;
    float sv = s[i];
    normed[f * NB * DD + i] = sv / (snrm[n] + 1e-10f);
    float old = mem[f * NB * DD + i];
    mem[f * NB * DD + i] = dec * old + (1.0f - dec) * sv;
  }
}

// born -> scr_born; 12 moment-partials of u=exp(born) per block; Gram in block 0.
__global__ __launch_bounds__(256) void k_born(const float4* __restrict__ E4,
                                              const float4* __restrict__ N4,
                                              const float* __restrict__ wbub,
                                              float* __restrict__ scr) {
  const int tid = threadIdx.x, lane = tid & 63, wave = tid >> 6;
  float* born = scr + SCR_BORN;
  float4 nr0[9], nr1[9];
#pragma unroll
  for (int j = 0; j < 9; j++) {
    nr0[j] = N4[j * 128 + lane];
    nr1[j] = N4[j * 128 + 64 + lane];
  }
  __shared__ float w9[9];
  __shared__ float sb2[12][4];
  if (tid < 9) w9[tid] = wbub[tid];
  __syncthreads();
  float pu0 = 0.f, pu1 = 0.f, pu2 = 0.f;
  float pub0 = 0.f, pub1 = 0.f, pub2 = 0.f;
  float puu0 = 0.f, puu1 = 0.f, puu2 = 0.f;
  float pc01 = 0.f, pc02 = 0.f, pc12 = 0.f;
  const int vbase = blockIdx.x * 16 + wave * 4;
#pragma unroll
  for (int r = 0; r < 4; r++) {
    int v = vbase + r;
    float4 a0 = E4[v * 128 + lane];
    float4 a1 = E4[v * 128 + 64 + lane];
    float acc[9];
#pragma unroll
    for (int j = 0; j < 9; j++) {
      float4 p = nr0[j], q = nr1[j];
      acc[j] = a0.x * p.x + a0.y * p.y + a0.z * p.z + a0.w * p.w +
               a1.x * q.x + a1.y * q.y + a1.z * q.z + a1.w * q.w;
    }
#pragma unroll
    for (int j = 0; j < 9; j++) {
      float a = acc[j];
#pragma unroll
      for (int off = 32; off; off >>= 1) a += __shfl_down(a, off, 64);
      acc[j] = a;
    }
    if (lane == 0) {
      float b0 = w9[0] * acc[0] * acc[0] + w9[1] * acc[1] * acc[1] + w9[2] * acc[2] * acc[2];
      float b1 = w9[3] * acc[3] * acc[3] + w9[4] * acc[4] * acc[4] + w9[5] * acc[5] * acc[5];
      float b2 = w9[6] * acc[6] * acc[6] + w9[7] * acc[7] * acc[7] + w9[8] * acc[8] * acc[8];
      born[v] = b0; born[VOCAB + v] = b1; born[2 * VOCAB + v] = b2;
      float u0 = expf(b0), u1 = expf(b1), u2 = expf(b2);
      pu0 += u0; pu1 += u1; pu2 += u2;
      pub0 += u0 * b0; pub1 += u1 * b1; pub2 += u2 * b2;
      puu0 += u0 * u0; puu1 += u1 * u1; puu2 += u2 * u2;
      pc01 += u0 * u1; pc02 += u0 * u2; pc12 += u1 * u2;
    }
  }
  if (lane == 0) {
    sb2[0][wave] = pu0;  sb2[1][wave] = pu1;  sb2[2][wave] = pu2;
    sb2[3][wave] = pub0; sb2[4][wave] = pub1; sb2[5][wave] = pub2;
    sb2[6][wave] = puu0; sb2[7][wave] = puu1; sb2[8][wave] = puu2;
    sb2[9][wave] = pc01; sb2[10][wave] = pc02; sb2[11][wave] = pc12;
  }
  __syncthreads();
  if (tid < 12) {
    float s = sb2[tid][0] + sb2[tid][1] + sb2[tid][2] + sb2[tid][3];
    scr[SCR_PART + tid * 2048 + blockIdx.x] = s;
  }
  // Gram (block 0 only): 45 pairs x 4 lanes
  if (blockIdx.x == 0 && tid < 180) {
    const int p = tid >> 2, sub = tid & 3;
    const float4* ni = N4 + (int)PI9[p] * 128;
    const float4* nj = N4 + (int)PJ9[p] * 128;
    float s = 0.f;
#pragma unroll
    for (int it = 0; it < 32; it++) {
      float4 a = ni[sub * 32 + it];
      float4 b = nj[sub * 32 + it];
      s += a.x * b.x + a.y * b.y + a.z * b.z + a.w * b.w;
    }
    s += __shfl_down(s, 2, 4);
    s += __shfl_down(s, 1, 4);
    if (sub == 0) scr[SCR_G + p] = s;
  }
}

// one wave: reduce 12x2048 partials -> all scalars + Jacobi -> S_rho
__global__ __launch_bounds__(64, 1) void k_scal(const float* __restrict__ scr,
                                                const float* __restrict__ wbub,
                                                const float* __restrict__ temp_p,
                                                float* __restrict__ o_w, float* __restrict__ o_sr,
                                                float* __restrict__ wmeta, float* __restrict__ logSf,
                                                float* __restrict__ coeff, float* __restrict__ srho_ws) {
  const int lane = threadIdx.x;
  __shared__ float r12[12];
  for (int j = 0; j < 12; j++) {
    const float* src = scr + SCR_PART + j * 2048;
    float s = 0.f;
    for (int b = lane; b < 2048; b += 64) s += src[b];
#pragma unroll
    for (int off = 32; off; off >>= 1) s += __shfl_down(s, off, 64);
    if (lane == 0) r12[j] = s;
  }
  __syncthreads();
  if (lane != 0) return;
  float S0 = r12[0], S1 = r12[1], S2 = r12[2];
  float lg0 = logf(S0), lg1 = logf(S1), lg2 = logf(S2);
  logSf[0] = lg0; logSf[1] = lg1; logSf[2] = lg2;
  float H0 = lg0 - r12[3] / S0;
  float H1 = lg1 - r12[4] / S1;
  float H2 = lg2 - r12[5] / S2;
  float c0 = 1.0f - H0 / MAX_ENT_F;
  float c1 = 1.0f - H1 / MAX_ENT_F;
  float c2 = 1.0f - H2 / MAX_ENT_F;
  float np0 = sqrtf(r12[6]) / S0 + 1e-10f;
  float np1 = sqrtf(r12[7]) / S1 + 1e-10f;
  float np2 = sqrtf(r12[8]) / S2 + 1e-10f;
  float A01 = (r12[9]  / (S0 * S1)) / (np0 * np1);
  float A02 = (r12[10] / (S0 * S2)) / (np0 * np2);
  float A12 = (r12[11] / (S1 * S2)) / (np1 * np2);
  float ag0 = 0.5f * (A01 + A02);
  float ag1 = 0.5f * (A01 + A12);
  float ag2 = 0.5f * (A02 + A12);
  float temp = fmaxf(fabsf(temp_p[0]), 0.01f);
  float z0 = c0 * ag0 / temp, z1 = c1 * ag1 / temp, z2 = c2 * ag2 / temp;
  float mz = fmaxf(z0, fmaxf(z1, z2));
  float e0 = expf(z0 - mz), e1 = expf(z1 - mz), e2 = expf(z2 - mz);
  float sd = e0 + e1 + e2;
  float wm[3] = { e0 / sd, e1 / sd, e2 / sd };
#pragma unroll
  for (int f = 0; f < 3; f++) { o_w[f] = wm[f]; wmeta[f] = wm[f]; }
  float c9[9];
#pragma unroll
  for (int f = 0; f < 3; f++)
#pragma unroll
    for (int n = 0; n < 3; n++) {
      c9[f * 3 + n] = wm[f] * wbub[f * 3 + n];
      coeff[f * 3 + n] = c9[f * 3 + n];
    }
  float sq9[9];
#pragma unroll
  for (int i = 0; i < 9; i++) sq9[i] = sqrtf(c9[i]);
  float M[81];
#pragma unroll
  for (int i = 0; i < 9; i++)
#pragma unroll
    for (int j = i; j < 9; j++) {
      float val = sq9[i] * sq9[j] * scr[SCR_G + i * (19 - i) / 2 + (j - i)];
      M[i * 9 + j] = val;
      M[j * 9 + i] = val;
    }
#pragma unroll 1
  for (int sweep = 0; sweep < 5; sweep++) {
#pragma unroll
    for (int pp = 0; pp < 8; pp++) {
#pragma unroll
      for (int q = pp + 1; q < 9; q++) {
        float apq = M[pp * 9 + q];
        float app = M[pp * 9 + pp], aqq = M[q * 9 + q];
        float denom = (fabsf(apq) > 1e-25f) ? apq : 1e-25f;
        float theta = 0.5f * (aqq - app) / denom;
        float tt = copysignf(1.0f, theta) / (fabsf(theta) + sqrtf(theta * theta + 1.f));
        float cc = 1.f / sqrtf(tt * tt + 1.f);
        float ssn = tt * cc;
#pragma unroll
        for (int k = 0; k < 9; k++) {
          float mpk = M[pp * 9 + k], mqk = M[q * 9 + k];
          M[pp * 9 + k] = cc * mpk - ssn * mqk;
          M[q * 9 + k]  = ssn * mpk + cc * mqk;
        }
#pragma unroll
        for (int k = 0; k < 9; k++) {
          float mkp = M[k * 9 + pp], mkq = M[k * 9 + q];
          M[k * 9 + pp] = cc * mkp - ssn * mkq;
          M[k * 9 + q]  = ssn * mkp + cc * mkq;
        }
      }
    }
  }
  float total = 503.0f * 1e-12f;
  float ev[9];
#pragma unroll
  for (int k = 0; k < 9; k++) { ev[k] = fmaxf(M[k * 9 + k], 1e-12f); total += ev[k]; }
  float S = 0.f;
#pragma unroll
  for (int k = 0; k < 9; k++) {
    float q = ev[k] / total;
    S -= q * fmaxf(logf(q), -100.0f);
  }
  float q0 = 1e-12f / total;
  S -= 503.0f * (q0 * fmaxf(logf(q0), -100.0f));
  o_sr[0] = S; srho_ws[0] = S;
}

// write per-foam probs p=exp(b-logS_f) to o_d; token-softmax partials (shift=0)
__global__ void k_t1(const float* __restrict__ scr, const float* __restrict__ logSf,
                     const float* __restrict__ wmeta, float* __restrict__ o_d,
                     float* __restrict__ wt) {
  const int tid = threadIdx.x;   // 128 blocks x 256
  __shared__ float sc[6];
  __shared__ float red[16];
  if (tid < 3) { sc[tid] = logSf[tid]; sc[3 + tid] = wmeta[tid]; }
  __syncthreads();
  const int v = blockIdx.x * 256 + tid;
  const float* born = scr + SCR_BORN;
  float b0 = born[v], b1 = born[VOCAB + v], b2 = born[2 * VOCAB + v];
  o_d[v]             = expf(b0 - sc[0]);
  o_d[VOCAB + v]     = expf(b1 - sc[1]);
  o_d[2 * VOCAB + v] = expf(b2 - sc[2]);
  float s = sc[3] * b0 + sc[4] * b1 + sc[5] * b2;
  float e = expf(s);
  float se  = blockReduceSum(e, red);
  float ses = blockReduceSum(e * s, red);
  if (tid == 0) { wt[blockIdx.x] = se; wt[128 + blockIdx.x] = ses; }
}

// reduce token partials -> logS_t, H, F
__global__ __launch_bounds__(64, 1) void k_t2(const float* __restrict__ wt,
                                              const float* __restrict__ srho_ws,
                                              float* __restrict__ logSt_ws,
                                              float* __restrict__ o_h, float* __restrict__ o_f) {
  const int lane = threadIdx.x;
  float a = 0.f, b = 0.f;
  for (int i = lane; i < 128; i += 64) { a += wt[i]; b += wt[128 + i]; }
#pragma unroll
  for (int off = 32; off; off >>= 1) { a += __shfl_down(a, off, 64); b += __shfl_down(b, off, 64); }
  if (lane == 0) {
    float lgS = logf(a);
    logSt_ws[0] = lgS;
    float H = lgS - b / a;
    o_h[0] = H;
    o_f[0] = H - srho_ws[0];
  }
}

// blocks <512: rho_meta rows; blocks >=512: o_tok = exp(sum w ln p + C)
__global__ void k_rho_tok(const float* __restrict__ normed, const float* __restrict__ coeff,
                          const float* __restrict__ wmeta, const float* __restrict__ logSf,
                          const float* __restrict__ logSt_ws, const float* __restrict__ o_d,
                          float* __restrict__ rho, float* __restrict__ o_tok) {
  const int tid = threadIdx.x;   // 640 blocks x 256
  if (blockIdx.x < 512) {
    const int i = blockIdx.x;
    __shared__ float cr[9];
    if (tid < 9) cr[tid] = coeff[tid] * normed[tid * DD + i];
    __syncthreads();
    for (int j = tid; j < DD; j += 256) {
      float s = 0.f;
#pragma unroll
      for (int k = 0; k < 9; k++) s += cr[k] * normed[k * DD + j];
      rho[i * DD + j] = s;
    }
  } else {
    __shared__ float sc[7];
    if (tid < 3) { sc[tid] = wmeta[tid]; sc[3 + tid] = logSf[tid]; }
    if (tid == 6) sc[6] = logSt_ws[0];
    __syncthreads();
    const int v = (blockIdx.x - 512) * 256 + tid;
    float C = sc[0] * sc[3] + sc[1] * sc[4] + sc[2] * sc[5] - sc[6];
    float s = sc[0] * logf(o_d[v]) + sc[1] * logf(o_d[VOCAB + v]) + sc[2] * logf(o_d[2 * VOCAB + v]);
    o_tok[v] = expf(s + C);
  }
}

// ---------------- host launcher ----------------
extern "C" void kernel_launch(void* const* d_in, const int* in_sizes, int n_in,
                              void* d_out, int out_size, void* d_ws, size_t ws_size,
                              hipStream_t stream) {
  const int*   tokens = (const int*)d_in[0];
  const float* E      = (const float*)d_in[1];
  const float* Ws     = (const float*)d_in[2];
  const float* temp_p = (const float*)d_in[3];
  const float* base_p = (const float*)d_in[4];
  const float* sens_p = (const float*)d_in[5];

  float* out   = (float*)d_out;
  float* o_tok = out;                             // [4][32768]
  float* o_rho = o_tok + SEQ * VOCAB;             // [4][512][512]
  float* o_w   = o_rho + (size_t)SEQ * DD * DD;   // [4][3]
  float* o_sr  = o_w + SEQ * NF;                  // [4]
  float* o_h   = o_sr + SEQ;                      // [4]
  float* o_f   = o_h + SEQ;                       // [4]
  float* o_d   = o_f + SEQ;                       // [4][3][32768]

  float* ws       = (float*)d_ws;
  float* w_mem    = ws;            // 4608
  float* w_decay  = ws + 4608;     // 3
  float* w_wbub   = ws + 4624;     // 9
  float* w_normed = ws + 4640;     // 4608 (16B-aligned)
  float* w_wmeta  = ws + 9984;     // 3
  float* w_logSf  = ws + 9988;     // 3
  float* w_coeff  = ws + 9992;     // 9
  float* w_srho   = ws + 10004;    // 1
  float* w_logSt  = ws + 10005;    // 1
  float* w_t      = ws + 10240;    // 256

  k_zero<<<18, 256, 0, stream>>>(w_mem, NF * NB * DD);

  for (int t = 0; t < SEQ; t++) {
    float* scr = o_rho + (size_t)t * DD * DD;   // scratch in not-yet-written rho slot
    k_states<<<dim3(9, 8), 256, 0, stream>>>(tokens, E, w_mem, Ws, base_p, sens_p,
                                             w_decay, scr + SCR_ST, t);
    k_equil<<<NF, 256, 0, stream>>>(scr + SCR_ST, w_mem, w_normed, w_wbub, w_decay);
    k_born<<<2048, 256, 0, stream>>>((const float4*)E, (const float4*)w_normed,
                                     w_wbub, scr);
    k_scal<<<1, 64, 0, stream>>>(scr, w_wbub, temp_p, o_w + t * NF, o_sr + t,
                                 w_wmeta, w_logSf, w_coeff, w_srho);
    k_t1<<<128, 256, 0, stream>>>(scr, w_logSf, w_wmeta,
                                  o_d + (size_t)t * NF * VOCAB, w_t);
    k_t2<<<1, 64, 0, stream>>>(w_t, w_srho, w_logSt, o_h + t, o_f + t);
    k_rho_tok<<<640, 256, 0, stream>>>(w_normed, w_coeff, w_wmeta, w_logSf, w_logSt,
                                       o_d + (size_t)t * NF * VOCAB,
                                       scr, o_tok + (size_t)t * VOCAB);
  }
}

// Round 5
// 564.308 us; speedup vs baseline: 2.2667x; 1.7119x over previous
//
#include <hip/hip_runtime.h>
#include <math.h>

#define VOCAB 32768
#define DD 512
#define NB 3
#define NF 3
#define SEQ 4
#define MAX_ENT_F 10.3972077083991790f

// scratch layout inside o_rho[t] (262144 floats, dead until k_rho_tok):
#define SCR_ST   0        // [9][8][512] states partials = 36864
#define SCR_PART 36864    // [12][2048] born-moment partials = 24576
#define SCR_G    61440    // [45] Gram
#define SCR_BORN 65536    // [3][VOCAB] = 98304

// pair index tables for i<=j over 9 (45 pairs)
__device__ const unsigned char PI9[45] = {
  0,0,0,0,0,0,0,0,0, 1,1,1,1,1,1,1,1, 2,2,2,2,2,2,2, 3,3,3,3,3,3,
  4,4,4,4,4, 5,5,5,5, 6,6,6, 7,7, 8};
__device__ const unsigned char PJ9[45] = {
  0,1,2,3,4,5,6,7,8, 1,2,3,4,5,6,7,8, 2,3,4,5,6,7,8, 3,4,5,6,7,8,
  4,5,6,7,8, 5,6,7,8, 6,7,8, 7,8, 8};

__device__ __forceinline__ float blockReduceSum(float v, float* sh) {
  int lane = threadIdx.x & 63;
  int wid  = threadIdx.x >> 6;
#pragma unroll
  for (int off = 32; off; off >>= 1) v += __shfl_down(v, off, 64);
  __syncthreads();
  if (lane == 0) sh[wid] = v;
  __syncthreads();
  int nw = blockDim.x >> 6;
  float r = 0.0f;
  if ((int)threadIdx.x < nw) r = sh[threadIdx.x];
  if (wid == 0) {
#pragma unroll
    for (int off = 8; off; off >>= 1) r += __shfl_down(r, off, 64);
    if (lane == 0) sh[0] = r;
  }
  __syncthreads();
  return sh[0];
}

__global__ void k_zero(float* p, int n) {
  int i = blockIdx.x * blockDim.x + threadIdx.x;
  if (i < n) p[i] = 0.0f;
}

// pre (redundant per block) + states K-chunk GEMV partials.
// grid (9, 8): fn = f*3+n, dc = K-chunk. 256 threads.
__global__ void k_states(const int* __restrict__ tokens, const float* __restrict__ E,
                         const float* __restrict__ mem, const float* __restrict__ Ws,
                         const float* __restrict__ base_p, const float* __restrict__ sens_p,
                         float* __restrict__ decayArr, float* __restrict__ scr_st, int t) {
  const int fn = blockIdx.x, dc = blockIdx.y, tid = threadIdx.x;
  const int f = fn / NB;
  const int d0 = dc * 64;
  __shared__ float smean[DD];
  __shared__ float xin_loc[64];
  __shared__ float red[16];
  __shared__ float s_decay;
  const float* x = E + (size_t)tokens[t] * DD;
  const float* m = mem + f * (NB * DD);
  for (int d = tid; d < DD; d += 256)
    smean[d] = (m[d] + m[DD + d] + m[2 * DD + d]) * (1.0f / 3.0f);
  __syncthreads();
  float pxm = 0.f, pxx = 0.f, pmm = 0.f;
  for (int d = tid; d < DD; d += 256) {
    float xv = x[d], mv = smean[d];
    pxm += xv * mv; pxx += xv * xv; pmm += mv * mv;
  }
  float sxm = blockReduceSum(pxm, red);
  float sxx = blockReduceSum(pxx, red);
  float smm = blockReduceSum(pmm, red);
  if (tid == 0) {
    float mem_norm = sqrtf(smm) + 1e-10f;
    float x_norm   = sqrtf(sxx) + 1e-10f;
    float novelty  = (mem_norm > 1e-8f) ? (1.0f - sxm / (x_norm * mem_norm)) : 1.0f;
    float sens = fabsf(sens_p[0]);
    float z = base_p[0] - sens * novelty;
    float dec = 1.0f / (1.0f + expf(-z));
    if (dc == 0 && fn % NB == 0) decayArr[f] = dec;
    s_decay = dec;
  }
  __syncthreads();
  if (tid < 64) xin_loc[tid] = x[d0 + tid] + s_decay * smean[d0 + tid];
  __syncthreads();
  const float* W = Ws + (size_t)fn * DD * DD + (size_t)d0 * DD;
  float acc0 = 0.f, acc1 = 0.f;
#pragma unroll 8
  for (int dd = 0; dd < 64; dd++) {
    float xv = xin_loc[dd];
    acc0 += xv * W[dd * DD + tid];
    acc1 += xv * W[dd * DD + tid + 256];
  }
  float* o = scr_st + (fn * 8 + dc) * DD;
  o[tid] = acc0;
  o[tid + 256] = acc1;
}

// sum K-chunks, equilibrate, norms, bubble weights, normed, memory update
__global__ void k_equil(const float* __restrict__ scr_st, float* __restrict__ mem,
                        float* __restrict__ normed, float* __restrict__ wbub,
                        const float* __restrict__ decayArr) {
  const int f = blockIdx.x, tid = threadIdx.x;   // 256 threads
  __shared__ float s[NB * DD];
  __shared__ float red[16];
  __shared__ float snrm[NB];
  for (int i = tid; i < NB * DD; i += 256) {
    int n = i >> 9, e = i & 511;
    const float* src = scr_st + ((f * NB + n) * 8) * DD + e;
    float acc = 0.f;
#pragma unroll
    for (int dc = 0; dc < 8; dc++) acc += src[dc * DD];
    s[i] = acc;
  }
  __syncthreads();
  for (int e = tid; e < DD; e += 256) {
    float a = s[e], b = s[DD + e], c = s[2 * DD + e];
#pragma unroll
    for (int it = 0; it < 3; it++) {
      float mn = (a + b + c) * (1.0f / 3.0f);
      a += 0.3f * (mn - a);
      b += 0.3f * (mn - b);
      c += 0.3f * (mn - c);
    }
    s[e] = a; s[DD + e] = b; s[2 * DD + e] = c;
  }
  __syncthreads();
  for (int n = 0; n < NB; n++) {
    float p = 0.f;
    for (int e = tid; e < DD; e += 256) { float v = s[n * DD + e]; p += v * v; }
    float ss = blockReduceSum(p, red);
    if (tid == 0) snrm[n] = sqrtf(ss);
  }
  __syncthreads();
  if (tid == 0) {
    float n0 = snrm[0], n1 = snrm[1], n2 = snrm[2];
    float mx = fmaxf(2.0f * n0, fmaxf(2.0f * n1, 2.0f * n2));
    float e0 = expf(2.0f * n0 - mx), e1 = expf(2.0f * n1 - mx), e2 = expf(2.0f * n2 - mx);
    float sd = e0 + e1 + e2;
    wbub[f * NB + 0] = e0 / sd;
    wbub[f * NB + 1] = e1 / sd;
    wbub[f * NB + 2] = e2 / sd;
  }
  float dec = decayArr[f];
  for (int i = tid; i < NB * DD; i += 256) {
    int n = i >> 9;
    float sv = s[i];
    normed[f * NB * DD + i] = sv / (snrm[n] + 1e-10f);
    float old = mem[f * NB * DD + i];
    mem[f * NB * DD + i] = dec * old + (1.0f - dec) * sv;
  }
}

// born -> scr_born; 12 moment-partials of u=exp(born) per block; Gram in block 0.
__global__ __launch_bounds__(256) void k_born(const float4* __restrict__ E4,
                                              const float4* __restrict__ N4,
                                              const float* __restrict__ wbub,
                                              float* __restrict__ scr) {
  const int tid = threadIdx.x, lane = tid & 63, wave = tid >> 6;
  float* born = scr + SCR_BORN;
  float4 nr0[9], nr1[9];
#pragma unroll
  for (int j = 0; j < 9; j++) {
    nr0[j] = N4[j * 128 + lane];
    nr1[j] = N4[j * 128 + 64 + lane];
  }
  __shared__ float w9[9];
  __shared__ float sb2[12][4];
  if (tid < 9) w9[tid] = wbub[tid];
  __syncthreads();
  float pu0 = 0.f, pu1 = 0.f, pu2 = 0.f;
  float pub0 = 0.f, pub1 = 0.f, pub2 = 0.f;
  float puu0 = 0.f, puu1 = 0.f, puu2 = 0.f;
  float pc01 = 0.f, pc02 = 0.f, pc12 = 0.f;
  const int vbase = blockIdx.x * 16 + wave * 4;
#pragma unroll
  for (int r = 0; r < 4; r++) {
    int v = vbase + r;
    float4 a0 = E4[v * 128 + lane];
    float4 a1 = E4[v * 128 + 64 + lane];
    float acc[9];
#pragma unroll
    for (int j = 0; j < 9; j++) {
      float4 p = nr0[j], q = nr1[j];
      acc[j] = a0.x * p.x + a0.y * p.y + a0.z * p.z + a0.w * p.w +
               a1.x * q.x + a1.y * q.y + a1.z * q.z + a1.w * q.w;
    }
#pragma unroll
    for (int j = 0; j < 9; j++) {
      float a = acc[j];
#pragma unroll
      for (int off = 32; off; off >>= 1) a += __shfl_down(a, off, 64);
      acc[j] = a;
    }
    if (lane == 0) {
      float b0 = w9[0] * acc[0] * acc[0] + w9[1] * acc[1] * acc[1] + w9[2] * acc[2] * acc[2];
      float b1 = w9[3] * acc[3] * acc[3] + w9[4] * acc[4] * acc[4] + w9[5] * acc[5] * acc[5];
      float b2 = w9[6] * acc[6] * acc[6] + w9[7] * acc[7] * acc[7] + w9[8] * acc[8] * acc[8];
      born[v] = b0; born[VOCAB + v] = b1; born[2 * VOCAB + v] = b2;
      float u0 = expf(b0), u1 = expf(b1), u2 = expf(b2);
      pu0 += u0; pu1 += u1; pu2 += u2;
      pub0 += u0 * b0; pub1 += u1 * b1; pub2 += u2 * b2;
      puu0 += u0 * u0; puu1 += u1 * u1; puu2 += u2 * u2;
      pc01 += u0 * u1; pc02 += u0 * u2; pc12 += u1 * u2;
    }
  }
  if (lane == 0) {
    sb2[0][wave] = pu0;  sb2[1][wave] = pu1;  sb2[2][wave] = pu2;
    sb2[3][wave] = pub0; sb2[4][wave] = pub1; sb2[5][wave] = pub2;
    sb2[6][wave] = puu0; sb2[7][wave] = puu1; sb2[8][wave] = puu2;
    sb2[9][wave] = pc01; sb2[10][wave] = pc02; sb2[11][wave] = pc12;
  }
  __syncthreads();
  if (tid < 12) {
    float s = sb2[tid][0] + sb2[tid][1] + sb2[tid][2] + sb2[tid][3];
    scr[SCR_PART + tid * 2048 + blockIdx.x] = s;
  }
  // Gram (block 0 only): 45 pairs x 4 lanes
  if (blockIdx.x == 0 && tid < 180) {
    const int p = tid >> 2, sub = tid & 3;
    const float4* ni = N4 + (int)PI9[p] * 128;
    const float4* nj = N4 + (int)PJ9[p] * 128;
    float s = 0.f;
#pragma unroll
    for (int it = 0; it < 32; it++) {
      float4 a = ni[sub * 32 + it];
      float4 b = nj[sub * 32 + it];
      s += a.x * b.x + a.y * b.y + a.z * b.z + a.w * b.w;
    }
    s += __shfl_down(s, 2, 4);
    s += __shfl_down(s, 1, 4);
    if (sub == 0) scr[SCR_G + p] = s;
  }
}

// One Jacobi rotation on pivot (APP,APQ,AQQ) touching 7 off-pairs — all args are
// NAMED scalar variables, so the matrix lives in SSA registers (cannot spill
// without real pressure). Exact tangent form for the diagonal.
#define ROT(APP,APQ,AQQ,P1,Q1,P2,Q2,P3,Q3,P4,Q4,P5,Q5,P6,Q6,P7,Q7) do {           \
    float apq_ = APQ;                                                               \
    float den_ = (fabsf(apq_) > 1e-25f) ? apq_ : 1e-25f;                            \
    float th_  = 0.5f * (AQQ - APP) / den_;                                         \
    float tt_  = copysignf(1.0f, th_) / (fabsf(th_) + sqrtf(th_ * th_ + 1.f));      \
    float cc_  = 1.f / sqrtf(tt_ * tt_ + 1.f);                                      \
    float sn_  = tt_ * cc_;                                                         \
    APP -= tt_ * apq_;  AQQ += tt_ * apq_;  APQ = 0.0f;                             \
    float a_, b_;                                                                   \
    a_ = P1; b_ = Q1; P1 = cc_ * a_ - sn_ * b_; Q1 = sn_ * a_ + cc_ * b_;           \
    a_ = P2; b_ = Q2; P2 = cc_ * a_ - sn_ * b_; Q2 = sn_ * a_ + cc_ * b_;           \
    a_ = P3; b_ = Q3; P3 = cc_ * a_ - sn_ * b_; Q3 = sn_ * a_ + cc_ * b_;           \
    a_ = P4; b_ = Q4; P4 = cc_ * a_ - sn_ * b_; Q4 = sn_ * a_ + cc_ * b_;           \
    a_ = P5; b_ = Q5; P5 = cc_ * a_ - sn_ * b_; Q5 = sn_ * a_ + cc_ * b_;           \
    a_ = P6; b_ = Q6; P6 = cc_ * a_ - sn_ * b_; Q6 = sn_ * a_ + cc_ * b_;           \
    a_ = P7; b_ = Q7; P7 = cc_ * a_ - sn_ * b_; Q7 = sn_ * a_ + cc_ * b_;           \
  } while (0)

// reduce 12x2048 partials (256 thr) -> all scalars; lane 0 runs scalarized Jacobi
__global__ __launch_bounds__(256, 1) void k_scal(const float* __restrict__ scr,
                                                 const float* __restrict__ wbub,
                                                 const float* __restrict__ temp_p,
                                                 float* __restrict__ o_w, float* __restrict__ o_sr,
                                                 float* __restrict__ wmeta, float* __restrict__ logSf,
                                                 float* __restrict__ coeff, float* __restrict__ srho_ws) {
  const int tid = threadIdx.x;
  __shared__ float r12[12];
  __shared__ float red[16];
  for (int j = 0; j < 12; j++) {
    const float* src = scr + SCR_PART + j * 2048;
    float s = 0.f;
#pragma unroll
    for (int b = 0; b < 8; b++) s += src[tid + b * 256];
    float tot = blockReduceSum(s, red);
    if (tid == 0) r12[j] = tot;
  }
  __syncthreads();
  if (tid != 0) return;
  float S0 = r12[0], S1 = r12[1], S2 = r12[2];
  float lg0 = logf(S0), lg1 = logf(S1), lg2 = logf(S2);
  logSf[0] = lg0; logSf[1] = lg1; logSf[2] = lg2;
  float H0 = lg0 - r12[3] / S0;
  float H1 = lg1 - r12[4] / S1;
  float H2 = lg2 - r12[5] / S2;
  float c0 = 1.0f - H0 / MAX_ENT_F;
  float c1 = 1.0f - H1 / MAX_ENT_F;
  float c2 = 1.0f - H2 / MAX_ENT_F;
  float np0 = sqrtf(r12[6]) / S0 + 1e-10f;
  float np1 = sqrtf(r12[7]) / S1 + 1e-10f;
  float np2 = sqrtf(r12[8]) / S2 + 1e-10f;
  float A01 = (r12[9]  / (S0 * S1)) / (np0 * np1);
  float A02 = (r12[10] / (S0 * S2)) / (np0 * np2);
  float A12 = (r12[11] / (S1 * S2)) / (np1 * np2);
  float ag0 = 0.5f * (A01 + A02);
  float ag1 = 0.5f * (A01 + A12);
  float ag2 = 0.5f * (A02 + A12);
  float temp = fmaxf(fabsf(temp_p[0]), 0.01f);
  float z0 = c0 * ag0 / temp, z1 = c1 * ag1 / temp, z2 = c2 * ag2 / temp;
  float mz = fmaxf(z0, fmaxf(z1, z2));
  float e0 = expf(z0 - mz), e1 = expf(z1 - mz), e2 = expf(z2 - mz);
  float sd = e0 + e1 + e2;
  float wm0 = e0 / sd, wm1 = e1 / sd, wm2 = e2 / sd;
  o_w[0] = wm0; o_w[1] = wm1; o_w[2] = wm2;
  wmeta[0] = wm0; wmeta[1] = wm1; wmeta[2] = wm2;
  float cf0 = wm0 * wbub[0], cf1 = wm0 * wbub[1], cf2 = wm0 * wbub[2];
  float cf3 = wm1 * wbub[3], cf4 = wm1 * wbub[4], cf5 = wm1 * wbub[5];
  float cf6 = wm2 * wbub[6], cf7 = wm2 * wbub[7], cf8 = wm2 * wbub[8];
  coeff[0] = cf0; coeff[1] = cf1; coeff[2] = cf2;
  coeff[3] = cf3; coeff[4] = cf4; coeff[5] = cf5;
  coeff[6] = cf6; coeff[7] = cf7; coeff[8] = cf8;
  float sq0 = sqrtf(cf0), sq1 = sqrtf(cf1), sq2 = sqrtf(cf2);
  float sq3 = sqrtf(cf3), sq4 = sqrtf(cf4), sq5 = sqrtf(cf5);
  float sq6 = sqrtf(cf6), sq7 = sqrtf(cf7), sq8 = sqrtf(cf8);
  const float* Gg = scr + SCR_G;
  // M packed upper triangle, fully scalarized
  float m00=sq0*sq0*Gg[0],  m01=sq0*sq1*Gg[1],  m02=sq0*sq2*Gg[2],  m03=sq0*sq3*Gg[3],  m04=sq0*sq4*Gg[4];
  float m05=sq0*sq5*Gg[5],  m06=sq0*sq6*Gg[6],  m07=sq0*sq7*Gg[7],  m08=sq0*sq8*Gg[8];
  float m11=sq1*sq1*Gg[9],  m12=sq1*sq2*Gg[10], m13=sq1*sq3*Gg[11], m14=sq1*sq4*Gg[12];
  float m15=sq1*sq5*Gg[13], m16=sq1*sq6*Gg[14], m17=sq1*sq7*Gg[15], m18=sq1*sq8*Gg[16];
  float m22=sq2*sq2*Gg[17], m23=sq2*sq3*Gg[18], m24=sq2*sq4*Gg[19], m25=sq2*sq5*Gg[20];
  float m26=sq2*sq6*Gg[21], m27=sq2*sq7*Gg[22], m28=sq2*sq8*Gg[23];
  float m33=sq3*sq3*Gg[24], m34=sq3*sq4*Gg[25], m35=sq3*sq5*Gg[26], m36=sq3*sq6*Gg[27];
  float m37=sq3*sq7*Gg[28], m38=sq3*sq8*Gg[29];
  float m44=sq4*sq4*Gg[30], m45=sq4*sq5*Gg[31], m46=sq4*sq6*Gg[32], m47=sq4*sq7*Gg[33];
  float m48=sq4*sq8*Gg[34];
  float m55=sq5*sq5*Gg[35], m56=sq5*sq6*Gg[36], m57=sq5*sq7*Gg[37], m58=sq5*sq8*Gg[38];
  float m66=sq6*sq6*Gg[39], m67=sq6*sq7*Gg[40], m68=sq6*sq8*Gg[41];
  float m77=sq7*sq7*Gg[42], m78=sq7*sq8*Gg[43];
  float m88=sq8*sq8*Gg[44];
#pragma unroll 1
  for (int sweep = 0; sweep < 5; sweep++) {
    ROT(m00,m01,m11, m02,m12, m03,m13, m04,m14, m05,m15, m06,m16, m07,m17, m08,m18);
    ROT(m00,m02,m22, m01,m12, m03,m23, m04,m24, m05,m25, m06,m26, m07,m27, m08,m28);
    ROT(m00,m03,m33, m01,m13, m02,m23, m04,m34, m05,m35, m06,m36, m07,m37, m08,m38);
    ROT(m00,m04,m44, m01,m14, m02,m24, m03,m34, m05,m45, m06,m46, m07,m47, m08,m48);
    ROT(m00,m05,m55, m01,m15, m02,m25, m03,m35, m04,m45, m06,m56, m07,m57, m08,m58);
    ROT(m00,m06,m66, m01,m16, m02,m26, m03,m36, m04,m46, m05,m56, m07,m67, m08,m68);
    ROT(m00,m07,m77, m01,m17, m02,m27, m03,m37, m04,m47, m05,m57, m06,m67, m08,m78);
    ROT(m00,m08,m88, m01,m18, m02,m28, m03,m38, m04,m48, m05,m58, m06,m68, m07,m78);
    ROT(m11,m12,m22, m01,m02, m13,m23, m14,m24, m15,m25, m16,m26, m17,m27, m18,m28);
    ROT(m11,m13,m33, m01,m03, m12,m23, m14,m34, m15,m35, m16,m36, m17,m37, m18,m38);
    ROT(m11,m14,m44, m01,m04, m12,m24, m13,m34, m15,m45, m16,m46, m17,m47, m18,m48);
    ROT(m11,m15,m55, m01,m05, m12,m25, m13,m35, m14,m45, m16,m56, m17,m57, m18,m58);
    ROT(m11,m16,m66, m01,m06, m12,m26, m13,m36, m14,m46, m15,m56, m17,m67, m18,m68);
    ROT(m11,m17,m77, m01,m07, m12,m27, m13,m37, m14,m47, m15,m57, m16,m67, m18,m78);
    ROT(m11,m18,m88, m01,m08, m12,m28, m13,m38, m14,m48, m15,m58, m16,m68, m17,m78);
    ROT(m22,m23,m33, m02,m03, m12,m13, m24,m34, m25,m35, m26,m36, m27,m37, m28,m38);
    ROT(m22,m24,m44, m02,m04, m12,m14, m23,m34, m25,m45, m26,m46, m27,m47, m28,m48);
    ROT(m22,m25,m55, m02,m05, m12,m15, m23,m35, m24,m45, m26,m56, m27,m57, m28,m58);
    ROT(m22,m26,m66, m02,m06, m12,m16, m23,m36, m24,m46, m25,m56, m27,m67, m28,m68);
    ROT(m22,m27,m77, m02,m07, m12,m17, m23,m37, m24,m47, m25,m57, m26,m67, m28,m78);
    ROT(m22,m28,m88, m02,m08, m12,m18, m23,m38, m24,m48, m25,m58, m26,m68, m27,m78);
    ROT(m33,m34,m44, m03,m04, m13,m14, m23,m24, m35,m45, m36,m46, m37,m47, m38,m48);
    ROT(m33,m35,m55, m03,m05, m13,m15, m23,m25, m34,m45, m36,m56, m37,m57, m38,m58);
    ROT(m33,m36,m66, m03,m06, m13,m16, m23,m26, m34,m46, m35,m56, m37,m67, m38,m68);
    ROT(m33,m37,m77, m03,m07, m13,m17, m23,m27, m34,m47, m35,m57, m36,m67, m38,m78);
    ROT(m33,m38,m88, m03,m08, m13,m18, m23,m28, m34,m48, m35,m58, m36,m68, m37,m78);
    ROT(m44,m45,m55, m04,m05, m14,m15, m24,m25, m34,m35, m46,m56, m47,m57, m48,m58);
    ROT(m44,m46,m66, m04,m06, m14,m16, m24,m26, m34,m36, m45,m56, m47,m67, m48,m68);
    ROT(m44,m47,m77, m04,m07, m14,m17, m24,m27, m34,m37, m45,m57, m46,m67, m48,m78);
    ROT(m44,m48,m88, m04,m08, m14,m18, m24,m28, m34,m38, m45,m58, m46,m68, m47,m78);
    ROT(m55,m56,m66, m05,m06, m15,m16, m25,m26, m35,m36, m45,m46, m57,m67, m58,m68);
    ROT(m55,m57,m77, m05,m07, m15,m17, m25,m27, m35,m37, m45,m47, m56,m67, m58,m78);
    ROT(m55,m58,m88, m05,m08, m15,m18, m25,m28, m35,m38, m45,m48, m56,m68, m57,m78);
    ROT(m66,m67,m77, m06,m07, m16,m17, m26,m27, m36,m37, m46,m47, m56,m57, m68,m78);
    ROT(m66,m68,m88, m06,m08, m16,m18, m26,m28, m36,m38, m46,m48, m56,m58, m67,m78);
    ROT(m77,m78,m88, m07,m08, m17,m18, m27,m28, m37,m38, m47,m48, m57,m58, m67,m68);
  }
  float total = 503.0f * 1e-12f;
  float ev0 = fmaxf(m00, 1e-12f), ev1 = fmaxf(m11, 1e-12f), ev2 = fmaxf(m22, 1e-12f);
  float ev3 = fmaxf(m33, 1e-12f), ev4 = fmaxf(m44, 1e-12f), ev5 = fmaxf(m55, 1e-12f);
  float ev6 = fmaxf(m66, 1e-12f), ev7 = fmaxf(m77, 1e-12f), ev8 = fmaxf(m88, 1e-12f);
  total += ev0 + ev1 + ev2 + ev3 + ev4 + ev5 + ev6 + ev7 + ev8;
  float S = 0.f;
#define ENT(EV) do { float q_ = (EV) / total; S -= q_ * fmaxf(logf(q_), -100.0f); } while (0)
  ENT(ev0); ENT(ev1); ENT(ev2); ENT(ev3); ENT(ev4); ENT(ev5); ENT(ev6); ENT(ev7); ENT(ev8);
#undef ENT
  float q0 = 1e-12f / total;
  S -= 503.0f * (q0 * fmaxf(logf(q0), -100.0f));
  o_sr[0] = S; srho_ws[0] = S;
}

// write per-foam probs p=exp(b-logS_f) to o_d; token-softmax partials (shift=0)
__global__ void k_t1(const float* __restrict__ scr, const float* __restrict__ logSf,
                     const float* __restrict__ wmeta, float* __restrict__ o_d,
                     float* __restrict__ wt) {
  const int tid = threadIdx.x;   // 128 blocks x 256
  __shared__ float sc[6];
  __shared__ float red[16];
  if (tid < 3) { sc[tid] = logSf[tid]; sc[3 + tid] = wmeta[tid]; }
  __syncthreads();
  const int v = blockIdx.x * 256 + tid;
  const float* born = scr + SCR_BORN;
  float b0 = born[v], b1 = born[VOCAB + v], b2 = born[2 * VOCAB + v];
  o_d[v]             = expf(b0 - sc[0]);
  o_d[VOCAB + v]     = expf(b1 - sc[1]);
  o_d[2 * VOCAB + v] = expf(b2 - sc[2]);
  float s = sc[3] * b0 + sc[4] * b1 + sc[5] * b2;
  float e = expf(s);
  float se  = blockReduceSum(e, red);
  float ses = blockReduceSum(e * s, red);
  if (tid == 0) { wt[blockIdx.x] = se; wt[128 + blockIdx.x] = ses; }
}

// reduce token partials -> logS_t, H, F
__global__ __launch_bounds__(64, 1) void k_t2(const float* __restrict__ wt,
                                              const float* __restrict__ srho_ws,
                                              float* __restrict__ logSt_ws,
                                              float* __restrict__ o_h, float* __restrict__ o_f) {
  const int lane = threadIdx.x;
  float a = 0.f, b = 0.f;
  for (int i = lane; i < 128; i += 64) { a += wt[i]; b += wt[128 + i]; }
#pragma unroll
  for (int off = 32; off; off >>= 1) { a += __shfl_down(a, off, 64); b += __shfl_down(b, off, 64); }
  if (lane == 0) {
    float lgS = logf(a);
    logSt_ws[0] = lgS;
    float H = lgS - b / a;
    o_h[0] = H;
    o_f[0] = H - srho_ws[0];
  }
}

// blocks <512: rho_meta rows; blocks >=512: o_tok = exp(sum w ln p + C)
__global__ void k_rho_tok(const float* __restrict__ normed, const float* __restrict__ coeff,
                          const float* __restrict__ wmeta, const float* __restrict__ logSf,
                          const float* __restrict__ logSt_ws, const float* __restrict__ o_d,
                          float* __restrict__ rho, float* __restrict__ o_tok) {
  const int tid = threadIdx.x;   // 640 blocks x 256
  if (blockIdx.x < 512) {
    const int i = blockIdx.x;
    __shared__ float cr[9];
    if (tid < 9) cr[tid] = coeff[tid] * normed[tid * DD + i];
    __syncthreads();
    for (int j = tid; j < DD; j += 256) {
      float s = 0.f;
#pragma unroll
      for (int k = 0; k < 9; k++) s += cr[k] * normed[k * DD + j];
      rho[i * DD + j] = s;
    }
  } else {
    __shared__ float sc[7];
    if (tid < 3) { sc[tid] = wmeta[tid]; sc[3 + tid] = logSf[tid]; }
    if (tid == 6) sc[6] = logSt_ws[0];
    __syncthreads();
    const int v = (blockIdx.x - 512) * 256 + tid;
    float C = sc[0] * sc[3] + sc[1] * sc[4] + sc[2] * sc[5] - sc[6];
    float s = sc[0] * logf(o_d[v]) + sc[1] * logf(o_d[VOCAB + v]) + sc[2] * logf(o_d[2 * VOCAB + v]);
    o_tok[v] = expf(s + C);
  }
}

// ---------------- host launcher ----------------
extern "C" void kernel_launch(void* const* d_in, const int* in_sizes, int n_in,
                              void* d_out, int out_size, void* d_ws, size_t ws_size,
                              hipStream_t stream) {
  const int*   tokens = (const int*)d_in[0];
  const float* E      = (const float*)d_in[1];
  const float* Ws     = (const float*)d_in[2];
  const float* temp_p = (const float*)d_in[3];
  const float* base_p = (const float*)d_in[4];
  const float* sens_p = (const float*)d_in[5];

  float* out   = (float*)d_out;
  float* o_tok = out;                             // [4][32768]
  float* o_rho = o_tok + SEQ * VOCAB;             // [4][512][512]
  float* o_w   = o_rho + (size_t)SEQ * DD * DD;   // [4][3]
  float* o_sr  = o_w + SEQ * NF;                  // [4]
  float* o_h   = o_sr + SEQ;                      // [4]
  float* o_f   = o_h + SEQ;                       // [4]
  float* o_d   = o_f + SEQ;                       // [4][3][32768]

  float* ws       = (float*)d_ws;
  float* w_mem    = ws;            // 4608
  float* w_decay  = ws + 4608;     // 3
  float* w_wbub   = ws + 4624;     // 9
  float* w_normed = ws + 4640;     // 4608 (16B-aligned)
  float* w_wmeta  = ws + 9984;     // 3
  float* w_logSf  = ws + 9988;     // 3
  float* w_coeff  = ws + 9992;     // 9
  float* w_srho   = ws + 10004;    // 1
  float* w_logSt  = ws + 10005;    // 1
  float* w_t      = ws + 10240;    // 256

  k_zero<<<18, 256, 0, stream>>>(w_mem, NF * NB * DD);

  for (int t = 0; t < SEQ; t++) {
    float* scr = o_rho + (size_t)t * DD * DD;   // scratch in not-yet-written rho slot
    k_states<<<dim3(9, 8), 256, 0, stream>>>(tokens, E, w_mem, Ws, base_p, sens_p,
                                             w_decay, scr + SCR_ST, t);
    k_equil<<<NF, 256, 0, stream>>>(scr + SCR_ST, w_mem, w_normed, w_wbub, w_decay);
    k_born<<<2048, 256, 0, stream>>>((const float4*)E, (const float4*)w_normed,
                                     w_wbub, scr);
    k_scal<<<1, 256, 0, stream>>>(scr, w_wbub, temp_p, o_w + t * NF, o_sr + t,
                                  w_wmeta, w_logSf, w_coeff, w_srho);
    k_t1<<<128, 256, 0, stream>>>(scr, w_logSf, w_wmeta,
                                  o_d + (size_t)t * NF * VOCAB, w_t);
    k_t2<<<1, 64, 0, stream>>>(w_t, w_srho, w_logSt, o_h + t, o_f + t);
    k_rho_tok<<<640, 256, 0, stream>>>(w_normed, w_coeff, w_wmeta, w_logSf, w_logSt,
                                       o_d + (size_t)t * NF * VOCAB,
                                       scr, o_tok + (size_t)t * VOCAB);
  }
}

// Round 6
// 439.322 us; speedup vs baseline: 2.9116x; 1.2845x over previous
//
#include <hip/hip_runtime.h>
#include <math.h>

#define VOCAB 32768
#define DD 512
#define NB 3
#define NF 3
#define SEQ 4
#define MAX_ENT_F 10.3972077083991790f

// scratch layout inside o_rho[t] (262144 floats, dead until k_rho_tok):
#define SCR_ST   0        // [9][8][512] states partials = 36864
#define SCR_PART 36864    // [12][2048] born-moment partials = 24576
#define SCR_G    61440    // [45] Gram
#define SCR_BORN 65536    // [3][VOCAB] = 98304

// pair index tables for i<=j over 9 (45 pairs)
__device__ const unsigned char PI9[45] = {
  0,0,0,0,0,0,0,0,0, 1,1,1,1,1,1,1,1, 2,2,2,2,2,2,2, 3,3,3,3,3,3,
  4,4,4,4,4, 5,5,5,5, 6,6,6, 7,7, 8};
__device__ const unsigned char PJ9[45] = {
  0,1,2,3,4,5,6,7,8, 1,2,3,4,5,6,7,8, 2,3,4,5,6,7,8, 3,4,5,6,7,8,
  4,5,6,7,8, 5,6,7,8, 6,7,8, 7,8, 8};

__device__ __forceinline__ float blockReduceSum(float v, float* sh) {
  int lane = threadIdx.x & 63;
  int wid  = threadIdx.x >> 6;
#pragma unroll
  for (int off = 32; off; off >>= 1) v += __shfl_down(v, off, 64);
  __syncthreads();
  if (lane == 0) sh[wid] = v;
  __syncthreads();
  int nw = blockDim.x >> 6;
  float r = 0.0f;
  if ((int)threadIdx.x < nw) r = sh[threadIdx.x];
  if (wid == 0) {
#pragma unroll
    for (int off = 8; off; off >>= 1) r += __shfl_down(r, off, 64);
    if (lane == 0) sh[0] = r;
  }
  __syncthreads();
  return sh[0];
}

__global__ void k_zero(float* p, int n) {
  int i = blockIdx.x * blockDim.x + threadIdx.x;
  if (i < n) p[i] = 0.0f;
}

// pre (redundant per block) + states K-chunk GEMV partials.
// grid (9, 8): fn = f*3+n, dc = K-chunk. 256 threads.
__global__ void k_states(const int* __restrict__ tokens, const float* __restrict__ E,
                         const float* __restrict__ mem, const float* __restrict__ Ws,
                         const float* __restrict__ base_p, const float* __restrict__ sens_p,
                         float* __restrict__ decayArr, float* __restrict__ scr_st, int t) {
  const int fn = blockIdx.x, dc = blockIdx.y, tid = threadIdx.x;
  const int f = fn / NB;
  const int d0 = dc * 64;
  __shared__ float smean[DD];
  __shared__ float xin_loc[64];
  __shared__ float red[16];
  __shared__ float s_decay;
  const float* x = E + (size_t)tokens[t] * DD;
  const float* m = mem + f * (NB * DD);
  for (int d = tid; d < DD; d += 256)
    smean[d] = (m[d] + m[DD + d] + m[2 * DD + d]) * (1.0f / 3.0f);
  __syncthreads();
  float pxm = 0.f, pxx = 0.f, pmm = 0.f;
  for (int d = tid; d < DD; d += 256) {
    float xv = x[d], mv = smean[d];
    pxm += xv * mv; pxx += xv * xv; pmm += mv * mv;
  }
  float sxm = blockReduceSum(pxm, red);
  float sxx = blockReduceSum(pxx, red);
  float smm = blockReduceSum(pmm, red);
  if (tid == 0) {
    float mem_norm = sqrtf(smm) + 1e-10f;
    float x_norm   = sqrtf(sxx) + 1e-10f;
    float novelty  = (mem_norm > 1e-8f) ? (1.0f - sxm / (x_norm * mem_norm)) : 1.0f;
    float sens = fabsf(sens_p[0]);
    float z = base_p[0] - sens * novelty;
    float dec = 1.0f / (1.0f + expf(-z));
    if (dc == 0 && fn % NB == 0) decayArr[f] = dec;
    s_decay = dec;
  }
  __syncthreads();
  if (tid < 64) xin_loc[tid] = x[d0 + tid] + s_decay * smean[d0 + tid];
  __syncthreads();
  const float* W = Ws + (size_t)fn * DD * DD + (size_t)d0 * DD;
  float acc0 = 0.f, acc1 = 0.f;
#pragma unroll 8
  for (int dd = 0; dd < 64; dd++) {
    float xv = xin_loc[dd];
    acc0 += xv * W[dd * DD + tid];
    acc1 += xv * W[dd * DD + tid + 256];
  }
  float* o = scr_st + (fn * 8 + dc) * DD;
  o[tid] = acc0;
  o[tid + 256] = acc1;
}

// sum K-chunks, equilibrate, norms, bubble weights, normed, memory update
__global__ void k_equil(const float* __restrict__ scr_st, float* __restrict__ mem,
                        float* __restrict__ normed, float* __restrict__ wbub,
                        const float* __restrict__ decayArr) {
  const int f = blockIdx.x, tid = threadIdx.x;   // 256 threads
  __shared__ float s[NB * DD];
  __shared__ float red[16];
  __shared__ float snrm[NB];
  for (int i = tid; i < NB * DD; i += 256) {
    int n = i >> 9, e = i & 511;
    const float* src = scr_st + ((f * NB + n) * 8) * DD + e;
    float acc = 0.f;
#pragma unroll
    for (int dc = 0; dc < 8; dc++) acc += src[dc * DD];
    s[i] = acc;
  }
  __syncthreads();
  for (int e = tid; e < DD; e += 256) {
    float a = s[e], b = s[DD + e], c = s[2 * DD + e];
#pragma unroll
    for (int it = 0; it < 3; it++) {
      float mn = (a + b + c) * (1.0f / 3.0f);
      a += 0.3f * (mn - a);
      b += 0.3f * (mn - b);
      c += 0.3f * (mn - c);
    }
    s[e] = a; s[DD + e] = b; s[2 * DD + e] = c;
  }
  __syncthreads();
  for (int n = 0; n < NB; n++) {
    float p = 0.f;
    for (int e = tid; e < DD; e += 256) { float v = s[n * DD + e]; p += v * v; }
    float ss = blockReduceSum(p, red);
    if (tid == 0) snrm[n] = sqrtf(ss);
  }
  __syncthreads();
  if (tid == 0) {
    float n0 = snrm[0], n1 = snrm[1], n2 = snrm[2];
    float mx = fmaxf(2.0f * n0, fmaxf(2.0f * n1, 2.0f * n2));
    float e0 = expf(2.0f * n0 - mx), e1 = expf(2.0f * n1 - mx), e2 = expf(2.0f * n2 - mx);
    float sd = e0 + e1 + e2;
    wbub[f * NB + 0] = e0 / sd;
    wbub[f * NB + 1] = e1 / sd;
    wbub[f * NB + 2] = e2 / sd;
  }
  float dec = decayArr[f];
  for (int i = tid; i < NB * DD; i += 256) {
    int n = i >> 9;
    float sv = s[i];
    normed[f * NB * DD + i] = sv / (snrm[n] + 1e-10f);
    float old = mem[f * NB * DD + i];
    mem[f * NB * DD + i] = dec * old + (1.0f - dec) * sv;
  }
}

// born -> scr_born; 12 moment-partials of u=exp(born) per block; Gram in block 0.
__global__ __launch_bounds__(256) void k_born(const float4* __restrict__ E4,
                                              const float4* __restrict__ N4,
                                              const float* __restrict__ wbub,
                                              float* __restrict__ scr) {
  const int tid = threadIdx.x, lane = tid & 63, wave = tid >> 6;
  float* born = scr + SCR_BORN;
  float4 nr0[9], nr1[9];
#pragma unroll
  for (int j = 0; j < 9; j++) {
    nr0[j] = N4[j * 128 + lane];
    nr1[j] = N4[j * 128 + 64 + lane];
  }
  __shared__ float w9[9];
  __shared__ float sb2[12][4];
  if (tid < 9) w9[tid] = wbub[tid];
  __syncthreads();
  float pu0 = 0.f, pu1 = 0.f, pu2 = 0.f;
  float pub0 = 0.f, pub1 = 0.f, pub2 = 0.f;
  float puu0 = 0.f, puu1 = 0.f, puu2 = 0.f;
  float pc01 = 0.f, pc02 = 0.f, pc12 = 0.f;
  const int vbase = blockIdx.x * 16 + wave * 4;
#pragma unroll
  for (int r = 0; r < 4; r++) {
    int v = vbase + r;
    float4 a0 = E4[v * 128 + lane];
    float4 a1 = E4[v * 128 + 64 + lane];
    float acc[9];
#pragma unroll
    for (int j = 0; j < 9; j++) {
      float4 p = nr0[j], q = nr1[j];
      acc[j] = a0.x * p.x + a0.y * p.y + a0.z * p.z + a0.w * p.w +
               a1.x * q.x + a1.y * q.y + a1.z * q.z + a1.w * q.w;
    }
#pragma unroll
    for (int j = 0; j < 9; j++) {
      float a = acc[j];
#pragma unroll
      for (int off = 32; off; off >>= 1) a += __shfl_down(a, off, 64);
      acc[j] = a;
    }
    if (lane == 0) {
      float b0 = w9[0] * acc[0] * acc[0] + w9[1] * acc[1] * acc[1] + w9[2] * acc[2] * acc[2];
      float b1 = w9[3] * acc[3] * acc[3] + w9[4] * acc[4] * acc[4] + w9[5] * acc[5] * acc[5];
      float b2 = w9[6] * acc[6] * acc[6] + w9[7] * acc[7] * acc[7] + w9[8] * acc[8] * acc[8];
      born[v] = b0; born[VOCAB + v] = b1; born[2 * VOCAB + v] = b2;
      float u0 = expf(b0), u1 = expf(b1), u2 = expf(b2);
      pu0 += u0; pu1 += u1; pu2 += u2;
      pub0 += u0 * b0; pub1 += u1 * b1; pub2 += u2 * b2;
      puu0 += u0 * u0; puu1 += u1 * u1; puu2 += u2 * u2;
      pc01 += u0 * u1; pc02 += u0 * u2; pc12 += u1 * u2;
    }
  }
  if (lane == 0) {
    sb2[0][wave] = pu0;  sb2[1][wave] = pu1;  sb2[2][wave] = pu2;
    sb2[3][wave] = pub0; sb2[4][wave] = pub1; sb2[5][wave] = pub2;
    sb2[6][wave] = puu0; sb2[7][wave] = puu1; sb2[8][wave] = puu2;
    sb2[9][wave] = pc01; sb2[10][wave] = pc02; sb2[11][wave] = pc12;
  }
  __syncthreads();
  if (tid < 12) {
    float s = sb2[tid][0] + sb2[tid][1] + sb2[tid][2] + sb2[tid][3];
    scr[SCR_PART + tid * 2048 + blockIdx.x] = s;
  }
  // Gram (block 0 only): 45 pairs x 4 lanes
  if (blockIdx.x == 0 && tid < 180) {
    const int p = tid >> 2, sub = tid & 3;
    const float4* ni = N4 + (int)PI9[p] * 128;
    const float4* nj = N4 + (int)PJ9[p] * 128;
    float s = 0.f;
#pragma unroll
    for (int it = 0; it < 32; it++) {
      float4 a = ni[sub * 32 + it];
      float4 b = nj[sub * 32 + it];
      s += a.x * b.x + a.y * b.y + a.z * b.z + a.w * b.w;
    }
    s += __shfl_down(s, 2, 4);
    s += __shfl_down(s, 1, 4);
    if (sub == 0) scr[SCR_G + p] = s;
  }
}

// One Jacobi rotation on named scalars; HW rcp/rsq/sqrt (1 instr, ~1ulp) keep
// the serial dependent chain short. Orthogonality is structural (c^2+s^2=1),
// so ~1e-7 rounding only perturbs convergence, not the preserved spectrum.
#define ROT(APP,APQ,AQQ,P1,Q1,P2,Q2,P3,Q3,P4,Q4,P5,Q5,P6,Q6,P7,Q7) do {           \
    float apq_ = APQ;                                                               \
    float den_ = (fabsf(apq_) > 1e-25f) ? apq_ : 1e-25f;                            \
    float th_  = 0.5f * (AQQ - APP) * __builtin_amdgcn_rcpf(den_);                  \
    float mag_ = __builtin_amdgcn_rcpf(fabsf(th_) +                                 \
                   __builtin_amdgcn_sqrtf(th_ * th_ + 1.f));                        \
    float tt_  = copysignf(mag_, th_);                                              \
    float cc_  = __builtin_amdgcn_rsqf(tt_ * tt_ + 1.f);                            \
    float sn_  = tt_ * cc_;                                                         \
    APP -= tt_ * apq_;  AQQ += tt_ * apq_;  APQ = 0.0f;                             \
    float a_, b_;                                                                   \
    a_ = P1; b_ = Q1; P1 = cc_ * a_ - sn_ * b_; Q1 = sn_ * a_ + cc_ * b_;           \
    a_ = P2; b_ = Q2; P2 = cc_ * a_ - sn_ * b_; Q2 = sn_ * a_ + cc_ * b_;           \
    a_ = P3; b_ = Q3; P3 = cc_ * a_ - sn_ * b_; Q3 = sn_ * a_ + cc_ * b_;           \
    a_ = P4; b_ = Q4; P4 = cc_ * a_ - sn_ * b_; Q4 = sn_ * a_ + cc_ * b_;           \
    a_ = P5; b_ = Q5; P5 = cc_ * a_ - sn_ * b_; Q5 = sn_ * a_ + cc_ * b_;           \
    a_ = P6; b_ = Q6; P6 = cc_ * a_ - sn_ * b_; Q6 = sn_ * a_ + cc_ * b_;           \
    a_ = P7; b_ = Q7; P7 = cc_ * a_ - sn_ * b_; Q7 = sn_ * a_ + cc_ * b_;           \
  } while (0)

// 4 waves x 3 rounds reduce 12x2048 partials (no barriers); lane 0 runs Jacobi
__global__ __launch_bounds__(256, 1) void k_scal(const float* __restrict__ scr,
                                                 const float* __restrict__ wbub,
                                                 const float* __restrict__ temp_p,
                                                 float* __restrict__ o_w, float* __restrict__ o_sr,
                                                 float* __restrict__ wmeta, float* __restrict__ logSf,
                                                 float* __restrict__ coeff, float* __restrict__ srho_ws) {
  const int tid = threadIdx.x, lane = tid & 63, wave = tid >> 6;
  __shared__ float r12[12];
#pragma unroll
  for (int jj = 0; jj < 3; jj++) {
    const int j = wave * 3 + jj;
    const float* src = scr + SCR_PART + j * 2048;
    float s = 0.f;
#pragma unroll
    for (int b = 0; b < 32; b++) s += src[lane + b * 64];
#pragma unroll
    for (int off = 32; off; off >>= 1) s += __shfl_down(s, off, 64);
    if (lane == 0) r12[j] = s;
  }
  __syncthreads();
  if (tid != 0) return;
  float S0 = r12[0], S1 = r12[1], S2 = r12[2];
  float lg0 = logf(S0), lg1 = logf(S1), lg2 = logf(S2);
  logSf[0] = lg0; logSf[1] = lg1; logSf[2] = lg2;
  float H0 = lg0 - r12[3] / S0;
  float H1 = lg1 - r12[4] / S1;
  float H2 = lg2 - r12[5] / S2;
  float c0 = 1.0f - H0 / MAX_ENT_F;
  float c1 = 1.0f - H1 / MAX_ENT_F;
  float c2 = 1.0f - H2 / MAX_ENT_F;
  float np0 = sqrtf(r12[6]) / S0 + 1e-10f;
  float np1 = sqrtf(r12[7]) / S1 + 1e-10f;
  float np2 = sqrtf(r12[8]) / S2 + 1e-10f;
  float A01 = (r12[9]  / (S0 * S1)) / (np0 * np1);
  float A02 = (r12[10] / (S0 * S2)) / (np0 * np2);
  float A12 = (r12[11] / (S1 * S2)) / (np1 * np2);
  float ag0 = 0.5f * (A01 + A02);
  float ag1 = 0.5f * (A01 + A12);
  float ag2 = 0.5f * (A02 + A12);
  float temp = fmaxf(fabsf(temp_p[0]), 0.01f);
  float z0 = c0 * ag0 / temp, z1 = c1 * ag1 / temp, z2 = c2 * ag2 / temp;
  float mz = fmaxf(z0, fmaxf(z1, z2));
  float e0 = expf(z0 - mz), e1 = expf(z1 - mz), e2 = expf(z2 - mz);
  float sd = e0 + e1 + e2;
  float wm0 = e0 / sd, wm1 = e1 / sd, wm2 = e2 / sd;
  o_w[0] = wm0; o_w[1] = wm1; o_w[2] = wm2;
  wmeta[0] = wm0; wmeta[1] = wm1; wmeta[2] = wm2;
  float cf0 = wm0 * wbub[0], cf1 = wm0 * wbub[1], cf2 = wm0 * wbub[2];
  float cf3 = wm1 * wbub[3], cf4 = wm1 * wbub[4], cf5 = wm1 * wbub[5];
  float cf6 = wm2 * wbub[6], cf7 = wm2 * wbub[7], cf8 = wm2 * wbub[8];
  coeff[0] = cf0; coeff[1] = cf1; coeff[2] = cf2;
  coeff[3] = cf3; coeff[4] = cf4; coeff[5] = cf5;
  coeff[6] = cf6; coeff[7] = cf7; coeff[8] = cf8;
  float sq0 = sqrtf(cf0), sq1 = sqrtf(cf1), sq2 = sqrtf(cf2);
  float sq3 = sqrtf(cf3), sq4 = sqrtf(cf4), sq5 = sqrtf(cf5);
  float sq6 = sqrtf(cf6), sq7 = sqrtf(cf7), sq8 = sqrtf(cf8);
  const float* Gg = scr + SCR_G;
  // M packed upper triangle, fully scalarized
  float m00=sq0*sq0*Gg[0],  m01=sq0*sq1*Gg[1],  m02=sq0*sq2*Gg[2],  m03=sq0*sq3*Gg[3],  m04=sq0*sq4*Gg[4];
  float m05=sq0*sq5*Gg[5],  m06=sq0*sq6*Gg[6],  m07=sq0*sq7*Gg[7],  m08=sq0*sq8*Gg[8];
  float m11=sq1*sq1*Gg[9],  m12=sq1*sq2*Gg[10], m13=sq1*sq3*Gg[11], m14=sq1*sq4*Gg[12];
  float m15=sq1*sq5*Gg[13], m16=sq1*sq6*Gg[14], m17=sq1*sq7*Gg[15], m18=sq1*sq8*Gg[16];
  float m22=sq2*sq2*Gg[17], m23=sq2*sq3*Gg[18], m24=sq2*sq4*Gg[19], m25=sq2*sq5*Gg[20];
  float m26=sq2*sq6*Gg[21], m27=sq2*sq7*Gg[22], m28=sq2*sq8*Gg[23];
  float m33=sq3*sq3*Gg[24], m34=sq3*sq4*Gg[25], m35=sq3*sq5*Gg[26], m36=sq3*sq6*Gg[27];
  float m37=sq3*sq7*Gg[28], m38=sq3*sq8*Gg[29];
  float m44=sq4*sq4*Gg[30], m45=sq4*sq5*Gg[31], m46=sq4*sq6*Gg[32], m47=sq4*sq7*Gg[33];
  float m48=sq4*sq8*Gg[34];
  float m55=sq5*sq5*Gg[35], m56=sq5*sq6*Gg[36], m57=sq5*sq7*Gg[37], m58=sq5*sq8*Gg[38];
  float m66=sq6*sq6*Gg[39], m67=sq6*sq7*Gg[40], m68=sq6*sq8*Gg[41];
  float m77=sq7*sq7*Gg[42], m78=sq7*sq8*Gg[43];
  float m88=sq8*sq8*Gg[44];
#pragma unroll 1
  for (int sweep = 0; sweep < 5; sweep++) {
    ROT(m00,m01,m11, m02,m12, m03,m13, m04,m14, m05,m15, m06,m16, m07,m17, m08,m18);
    ROT(m00,m02,m22, m01,m12, m03,m23, m04,m24, m05,m25, m06,m26, m07,m27, m08,m28);
    ROT(m00,m03,m33, m01,m13, m02,m23, m04,m34, m05,m35, m06,m36, m07,m37, m08,m38);
    ROT(m00,m04,m44, m01,m14, m02,m24, m03,m34, m05,m45, m06,m46, m07,m47, m08,m48);
    ROT(m00,m05,m55, m01,m15, m02,m25, m03,m35, m04,m45, m06,m56, m07,m57, m08,m58);
    ROT(m00,m06,m66, m01,m16, m02,m26, m03,m36, m04,m46, m05,m56, m07,m67, m08,m68);
    ROT(m00,m07,m77, m01,m17, m02,m27, m03,m37, m04,m47, m05,m57, m06,m67, m08,m78);
    ROT(m00,m08,m88, m01,m18, m02,m28, m03,m38, m04,m48, m05,m58, m06,m68, m07,m78);
    ROT(m11,m12,m22, m01,m02, m13,m23, m14,m24, m15,m25, m16,m26, m17,m27, m18,m28);
    ROT(m11,m13,m33, m01,m03, m12,m23, m14,m34, m15,m35, m16,m36, m17,m37, m18,m38);
    ROT(m11,m14,m44, m01,m04, m12,m24, m13,m34, m15,m45, m16,m46, m17,m47, m18,m48);
    ROT(m11,m15,m55, m01,m05, m12,m25, m13,m35, m14,m45, m16,m56, m17,m57, m18,m58);
    ROT(m11,m16,m66, m01,m06, m12,m26, m13,m36, m14,m46, m15,m56, m17,m67, m18,m68);
    ROT(m11,m17,m77, m01,m07, m12,m27, m13,m37, m14,m47, m15,m57, m16,m67, m18,m78);
    ROT(m11,m18,m88, m01,m08, m12,m28, m13,m38, m14,m48, m15,m58, m16,m68, m17,m78);
    ROT(m22,m23,m33, m02,m03, m12,m13, m24,m34, m25,m35, m26,m36, m27,m37, m28,m38);
    ROT(m22,m24,m44, m02,m04, m12,m14, m23,m34, m25,m45, m26,m46, m27,m47, m28,m48);
    ROT(m22,m25,m55, m02,m05, m12,m15, m23,m35, m24,m45, m26,m56, m27,m57, m28,m58);
    ROT(m22,m26,m66, m02,m06, m12,m16, m23,m36, m24,m46, m25,m56, m27,m67, m28,m68);
    ROT(m22,m27,m77, m02,m07, m12,m17, m23,m37, m24,m47, m25,m57, m26,m67, m28,m78);
    ROT(m22,m28,m88, m02,m08, m12,m18, m23,m38, m24,m48, m25,m58, m26,m68, m27,m78);
    ROT(m33,m34,m44, m03,m04, m13,m14, m23,m24, m35,m45, m36,m46, m37,m47, m38,m48);
    ROT(m33,m35,m55, m03,m05, m13,m15, m23,m25, m34,m45, m36,m56, m37,m57, m38,m58);
    ROT(m33,m36,m66, m03,m06, m13,m16, m23,m26, m34,m46, m35,m56, m37,m67, m38,m68);
    ROT(m33,m37,m77, m03,m07, m13,m17, m23,m27, m34,m47, m35,m57, m36,m67, m38,m78);
    ROT(m33,m38,m88, m03,m08, m13,m18, m23,m28, m34,m48, m35,m58, m36,m68, m37,m78);
    ROT(m44,m45,m55, m04,m05, m14,m15, m24,m25, m34,m35, m46,m56, m47,m57, m48,m58);
    ROT(m44,m46,m66, m04,m06, m14,m16, m24,m26, m34,m36, m45,m56, m47,m67, m48,m68);
    ROT(m44,m47,m77, m04,m07, m14,m17, m24,m27, m34,m37, m45,m57, m46,m67, m48,m78);
    ROT(m44,m48,m88, m04,m08, m14,m18, m24,m28, m34,m38, m45,m58, m46,m68, m47,m78);
    ROT(m55,m56,m66, m05,m06, m15,m16, m25,m26, m35,m36, m45,m46, m57,m67, m58,m68);
    ROT(m55,m57,m77, m05,m07, m15,m17, m25,m27, m35,m37, m45,m47, m56,m67, m58,m78);
    ROT(m55,m58,m88, m05,m08, m15,m18, m25,m28, m35,m38, m45,m48, m56,m68, m57,m78);
    ROT(m66,m67,m77, m06,m07, m16,m17, m26,m27, m36,m37, m46,m47, m56,m57, m68,m78);
    ROT(m66,m68,m88, m06,m08, m16,m18, m26,m28, m36,m38, m46,m48, m56,m58, m67,m78);
    ROT(m77,m78,m88, m07,m08, m17,m18, m27,m28, m37,m38, m47,m48, m57,m58, m67,m68);
  }
  float total = 503.0f * 1e-12f;
  float ev0 = fmaxf(m00, 1e-12f), ev1 = fmaxf(m11, 1e-12f), ev2 = fmaxf(m22, 1e-12f);
  float ev3 = fmaxf(m33, 1e-12f), ev4 = fmaxf(m44, 1e-12f), ev5 = fmaxf(m55, 1e-12f);
  float ev6 = fmaxf(m66, 1e-12f), ev7 = fmaxf(m77, 1e-12f), ev8 = fmaxf(m88, 1e-12f);
  total += ev0 + ev1 + ev2 + ev3 + ev4 + ev5 + ev6 + ev7 + ev8;
  float S = 0.f;
#define ENT(EV) do { float q_ = (EV) / total; S -= q_ * fmaxf(logf(q_), -100.0f); } while (0)
  ENT(ev0); ENT(ev1); ENT(ev2); ENT(ev3); ENT(ev4); ENT(ev5); ENT(ev6); ENT(ev7); ENT(ev8);
#undef ENT
  float q0 = 1e-12f / total;
  S -= 503.0f * (q0 * fmaxf(logf(q0), -100.0f));
  o_sr[0] = S; srho_ws[0] = S;
}

// write per-foam probs p=exp(b-logS_f) to o_d; token-softmax partials (shift=0)
__global__ void k_t1(const float* __restrict__ scr, const float* __restrict__ logSf,
                     const float* __restrict__ wmeta, float* __restrict__ o_d,
                     float* __restrict__ wt) {
  const int tid = threadIdx.x;   // 128 blocks x 256
  __shared__ float sc[6];
  __shared__ float red[16];
  if (tid < 3) { sc[tid] = logSf[tid]; sc[3 + tid] = wmeta[tid]; }
  __syncthreads();
  const int v = blockIdx.x * 256 + tid;
  const float* born = scr + SCR_BORN;
  float b0 = born[v], b1 = born[VOCAB + v], b2 = born[2 * VOCAB + v];
  o_d[v]             = expf(b0 - sc[0]);
  o_d[VOCAB + v]     = expf(b1 - sc[1]);
  o_d[2 * VOCAB + v] = expf(b2 - sc[2]);
  float s = sc[3] * b0 + sc[4] * b1 + sc[5] * b2;
  float e = expf(s);
  float se  = blockReduceSum(e, red);
  float ses = blockReduceSum(e * s, red);
  if (tid == 0) { wt[blockIdx.x] = se; wt[128 + blockIdx.x] = ses; }
}

// blocks <512: rho_meta rows; blocks >=512: reduce wt -> logS_t, write o_tok
// (block 512 thread 0 also writes H and F = H - S_rho)
__global__ void k_rho_tok(const float* __restrict__ normed, const float* __restrict__ coeff,
                          const float* __restrict__ wmeta, const float* __restrict__ logSf,
                          const float* __restrict__ wt, const float* __restrict__ srho_ws,
                          const float* __restrict__ o_d,
                          float* __restrict__ rho, float* __restrict__ o_tok,
                          float* __restrict__ o_h, float* __restrict__ o_f) {
  const int tid = threadIdx.x;   // 640 blocks x 256
  if (blockIdx.x < 512) {
    const int i = blockIdx.x;
    __shared__ float cr[9];
    if (tid < 9) cr[tid] = coeff[tid] * normed[tid * DD + i];
    __syncthreads();
    for (int j = tid; j < DD; j += 256) {
      float s = 0.f;
#pragma unroll
      for (int k = 0; k < 9; k++) s += cr[k] * normed[k * DD + j];
      rho[i * DD + j] = s;
    }
  } else {
    __shared__ float sc[6];
    __shared__ float red[16];
    if (tid < 3) { sc[tid] = wmeta[tid]; sc[3 + tid] = logSf[tid]; }
    float a_in = (tid < 128) ? wt[tid] : 0.f;
    float b_in = (tid < 128) ? wt[128 + tid] : 0.f;
    float A = blockReduceSum(a_in, red);
    float B = blockReduceSum(b_in, red);
    float lgS = logf(A);
    const int v = (blockIdx.x - 512) * 256 + tid;
    float C = sc[0] * sc[3] + sc[1] * sc[4] + sc[2] * sc[5] - lgS;
    float s = sc[0] * logf(o_d[v]) + sc[1] * logf(o_d[VOCAB + v]) + sc[2] * logf(o_d[2 * VOCAB + v]);
    o_tok[v] = expf(s + C);
    if (blockIdx.x == 512 && tid == 0) {
      float H = lgS - B / A;
      o_h[0] = H;
      o_f[0] = H - srho_ws[0];
    }
  }
}

// ---------------- host launcher ----------------
extern "C" void kernel_launch(void* const* d_in, const int* in_sizes, int n_in,
                              void* d_out, int out_size, void* d_ws, size_t ws_size,
                              hipStream_t stream) {
  const int*   tokens = (const int*)d_in[0];
  const float* E      = (const float*)d_in[1];
  const float* Ws     = (const float*)d_in[2];
  const float* temp_p = (const float*)d_in[3];
  const float* base_p = (const float*)d_in[4];
  const float* sens_p = (const float*)d_in[5];

  float* out   = (float*)d_out;
  float* o_tok = out;                             // [4][32768]
  float* o_rho = o_tok + SEQ * VOCAB;             // [4][512][512]
  float* o_w   = o_rho + (size_t)SEQ * DD * DD;   // [4][3]
  float* o_sr  = o_w + SEQ * NF;                  // [4]
  float* o_h   = o_sr + SEQ;                      // [4]
  float* o_f   = o_h + SEQ;                       // [4]
  float* o_d   = o_f + SEQ;                       // [4][3][32768]

  float* ws       = (float*)d_ws;
  float* w_mem    = ws;            // 4608
  float* w_decay  = ws + 4608;     // 3
  float* w_wbub   = ws + 4624;     // 9
  float* w_normed = ws + 4640;     // 4608 (16B-aligned)
  float* w_wmeta  = ws + 9984;     // 3
  float* w_logSf  = ws + 9988;     // 3
  float* w_coeff  = ws + 9992;     // 9
  float* w_srho   = ws + 10004;    // 1
  float* w_t      = ws + 10240;    // 256

  k_zero<<<18, 256, 0, stream>>>(w_mem, NF * NB * DD);

  for (int t = 0; t < SEQ; t++) {
    float* scr = o_rho + (size_t)t * DD * DD;   // scratch in not-yet-written rho slot
    k_states<<<dim3(9, 8), 256, 0, stream>>>(tokens, E, w_mem, Ws, base_p, sens_p,
                                             w_decay, scr + SCR_ST, t);
    k_equil<<<NF, 256, 0, stream>>>(scr + SCR_ST, w_mem, w_normed, w_wbub, w_decay);
    k_born<<<2048, 256, 0, stream>>>((const float4*)E, (const float4*)w_normed,
                                     w_wbub, scr);
    k_scal<<<1, 256, 0, stream>>>(scr, w_wbub, temp_p, o_w + t * NF, o_sr + t,
                                  w_wmeta, w_logSf, w_coeff, w_srho);
    k_t1<<<128, 256, 0, stream>>>(scr, w_logSf, w_wmeta,
                                  o_d + (size_t)t * NF * VOCAB, w_t);
    k_rho_tok<<<640, 256, 0, stream>>>(w_normed, w_coeff, w_wmeta, w_logSf, w_t, w_srho,
                                       o_d + (size_t)t * NF * VOCAB,
                                       scr, o_tok + (size_t)t * VOCAB, o_h + t, o_f + t);
  }
}